// Round 1
// baseline (21733.751 us; speedup 1.0000x reference)
//
#include <hip/hip_runtime.h>
#include <cstdint>
#include <cstddef>

// Problem constants (fixed by setup_inputs)
constexpr int NROWS = 32768;   // N
constexpr int DIN   = 2048;    // in_dim
constexpr int HID   = 1024;    // hid
constexpr int CS    = 2048;    // codebook size
constexpr int TOPM  = 256;

// =====================================================================
// GEMM: C[M][N] = act(A[M][K] @ B[K][N] + bias), fp32 in/out, fp64 acc.
// Tile 64x64, BK=16, 256 threads, 4x4 per thread.
// =====================================================================
template<bool RELU>
__global__ __launch_bounds__(256)
void gemm_bias_act(const float* __restrict__ A, const float* __restrict__ B,
                   const float* __restrict__ bias, float* __restrict__ C,
                   int M, int N, int K) {
  constexpr int BM = 64, BN = 64, BK = 16;
  __shared__ double As[BK][BM];
  __shared__ double Bs[BK][BN];
  const int tid = threadIdx.x;
  const int tx = tid & 15, ty = tid >> 4;
  const int row0 = blockIdx.y * BM, col0 = blockIdx.x * BN;

  double acc[4][4] = {};

  const int ar = tid >> 2;          // 0..63 (A row within tile)
  const int ak = (tid & 3) * 4;     // 0,4,8,12 (k offset)
  const int bk = tid >> 4;          // 0..15 (B k within tile)
  const int bc = (tid & 15) * 4;    // 0..60 (B col offset)

  for (int k0 = 0; k0 < K; k0 += BK) {
    const float4 av = *(const float4*)(A + (size_t)(row0 + ar) * K + k0 + ak);
    const float4 bv = *(const float4*)(B + (size_t)(k0 + bk) * N + col0 + bc);
    As[ak + 0][ar] = (double)av.x;
    As[ak + 1][ar] = (double)av.y;
    As[ak + 2][ar] = (double)av.z;
    As[ak + 3][ar] = (double)av.w;
    Bs[bk][bc + 0] = (double)bv.x;
    Bs[bk][bc + 1] = (double)bv.y;
    Bs[bk][bc + 2] = (double)bv.z;
    Bs[bk][bc + 3] = (double)bv.w;
    __syncthreads();
#pragma unroll
    for (int kk = 0; kk < BK; ++kk) {
      double a0 = As[kk][ty * 4 + 0], a1 = As[kk][ty * 4 + 1];
      double a2 = As[kk][ty * 4 + 2], a3 = As[kk][ty * 4 + 3];
      double b0 = Bs[kk][tx * 4 + 0], b1 = Bs[kk][tx * 4 + 1];
      double b2 = Bs[kk][tx * 4 + 2], b3 = Bs[kk][tx * 4 + 3];
      acc[0][0] = fma(a0, b0, acc[0][0]); acc[0][1] = fma(a0, b1, acc[0][1]);
      acc[0][2] = fma(a0, b2, acc[0][2]); acc[0][3] = fma(a0, b3, acc[0][3]);
      acc[1][0] = fma(a1, b0, acc[1][0]); acc[1][1] = fma(a1, b1, acc[1][1]);
      acc[1][2] = fma(a1, b2, acc[1][2]); acc[1][3] = fma(a1, b3, acc[1][3]);
      acc[2][0] = fma(a2, b0, acc[2][0]); acc[2][1] = fma(a2, b1, acc[2][1]);
      acc[2][2] = fma(a2, b2, acc[2][2]); acc[2][3] = fma(a2, b3, acc[2][3]);
      acc[3][0] = fma(a3, b0, acc[3][0]); acc[3][1] = fma(a3, b1, acc[3][1]);
      acc[3][2] = fma(a3, b2, acc[3][2]); acc[3][3] = fma(a3, b3, acc[3][3]);
    }
    __syncthreads();
  }

  const double bi0 = (double)bias[col0 + tx * 4 + 0];
  const double bi1 = (double)bias[col0 + tx * 4 + 1];
  const double bi2 = (double)bias[col0 + tx * 4 + 2];
  const double bi3 = (double)bias[col0 + tx * 4 + 3];
#pragma unroll
  for (int i = 0; i < 4; ++i) {
    double v0 = acc[i][0] + bi0, v1 = acc[i][1] + bi1;
    double v2 = acc[i][2] + bi2, v3 = acc[i][3] + bi3;
    if (RELU) {
      v0 = v0 > 0.0 ? v0 : 0.0; v1 = v1 > 0.0 ? v1 : 0.0;
      v2 = v2 > 0.0 ? v2 : 0.0; v3 = v3 > 0.0 ? v3 : 0.0;
    }
    float4 o;
    o.x = (float)v0; o.y = (float)v1; o.z = (float)v2; o.w = (float)v3;
    *(float4*)(C + (size_t)(row0 + ty * 4 + i) * N + col0 + tx * 4) = o;
  }
}

// =====================================================================
// Codebook inverse norms: invn[c] = 1/sqrt(sum(C[c]^2) + 1e-12), fp64.
// One wave per code row.
// =====================================================================
__global__ __launch_bounds__(256)
void codebook_invnorm(const float* __restrict__ Cb, double* __restrict__ invn, int K) {
  const int code = blockIdx.x * 4 + (threadIdx.x >> 6);
  const int lane = threadIdx.x & 63;
  const float* r = Cb + (size_t)code * K;
  double s = 0.0;
  for (int d = lane; d < K; d += 64) {
    double v = (double)r[d];
    s = fma(v, v, s);
  }
#pragma unroll
  for (int off = 32; off > 0; off >>= 1) s += __shfl_down(s, off, 64);
  if (lane == 0) invn[code] = 1.0 / sqrt(s + 1e-12);
}

// =====================================================================
// Distance tile + per-tile argmax: sims[r][c] = dot(Z[r], Cb[c]) * invn[c].
// 64 rows x 64 codes per block; per-row partial argmax written to
// pval/pidx [tile][row] (first-max-index tie semantics, codes ascending).
// =====================================================================
__global__ __launch_bounds__(256)
void dist_argmax(const float* __restrict__ Z, const float* __restrict__ Cb,
                 const double* __restrict__ invn,
                 double* __restrict__ pval, int* __restrict__ pidx, int K) {
  constexpr int BM = 64, BN = 64, BK = 16;
  __shared__ double As[BK][BM];
  __shared__ double Bs[BK][BN];
  __shared__ double rv[BM][17];
  __shared__ int    ri[BM][17];
  const int tid = threadIdx.x;
  const int tx = tid & 15, ty = tid >> 4;
  const int row0 = blockIdx.y * BM, col0 = blockIdx.x * BN;

  double acc[4][4] = {};
  const int ar = tid >> 2;
  const int ak = (tid & 3) * 4;

  for (int k0 = 0; k0 < K; k0 += BK) {
    const float4 av = *(const float4*)(Z  + (size_t)(row0 + ar) * K + k0 + ak);
    const float4 cv = *(const float4*)(Cb + (size_t)(col0 + ar) * K + k0 + ak);
    As[ak + 0][ar] = (double)av.x;
    As[ak + 1][ar] = (double)av.y;
    As[ak + 2][ar] = (double)av.z;
    As[ak + 3][ar] = (double)av.w;
    Bs[ak + 0][ar] = (double)cv.x;   // Bs[k][code]
    Bs[ak + 1][ar] = (double)cv.y;
    Bs[ak + 2][ar] = (double)cv.z;
    Bs[ak + 3][ar] = (double)cv.w;
    __syncthreads();
#pragma unroll
    for (int kk = 0; kk < BK; ++kk) {
      double a0 = As[kk][ty * 4 + 0], a1 = As[kk][ty * 4 + 1];
      double a2 = As[kk][ty * 4 + 2], a3 = As[kk][ty * 4 + 3];
      double b0 = Bs[kk][tx * 4 + 0], b1 = Bs[kk][tx * 4 + 1];
      double b2 = Bs[kk][tx * 4 + 2], b3 = Bs[kk][tx * 4 + 3];
      acc[0][0] = fma(a0, b0, acc[0][0]); acc[0][1] = fma(a0, b1, acc[0][1]);
      acc[0][2] = fma(a0, b2, acc[0][2]); acc[0][3] = fma(a0, b3, acc[0][3]);
      acc[1][0] = fma(a1, b0, acc[1][0]); acc[1][1] = fma(a1, b1, acc[1][1]);
      acc[1][2] = fma(a1, b2, acc[1][2]); acc[1][3] = fma(a1, b3, acc[1][3]);
      acc[2][0] = fma(a2, b0, acc[2][0]); acc[2][1] = fma(a2, b1, acc[2][1]);
      acc[2][2] = fma(a2, b2, acc[2][2]); acc[2][3] = fma(a2, b3, acc[2][3]);
      acc[3][0] = fma(a3, b0, acc[3][0]); acc[3][1] = fma(a3, b1, acc[3][1]);
      acc[3][2] = fma(a3, b2, acc[3][2]); acc[3][3] = fma(a3, b3, acc[3][3]);
    }
    __syncthreads();
  }

  const double in0 = invn[col0 + tx * 4 + 0];
  const double in1 = invn[col0 + tx * 4 + 1];
  const double in2 = invn[col0 + tx * 4 + 2];
  const double in3 = invn[col0 + tx * 4 + 3];
#pragma unroll
  for (int i = 0; i < 4; ++i) {
    double best = acc[i][0] * in0; int bi = col0 + tx * 4 + 0;
    double v;
    v = acc[i][1] * in1; if (v > best) { best = v; bi = col0 + tx * 4 + 1; }
    v = acc[i][2] * in2; if (v > best) { best = v; bi = col0 + tx * 4 + 2; }
    v = acc[i][3] * in3; if (v > best) { best = v; bi = col0 + tx * 4 + 3; }
    rv[ty * 4 + i][tx] = best;
    ri[ty * 4 + i][tx] = bi;
  }
  __syncthreads();
  if (tid < 64) {
    double best = rv[tid][0]; int bi = ri[tid][0];
    for (int t = 1; t < 16; ++t) {
      double v = rv[tid][t];
      if (v > best) { best = v; bi = ri[tid][t]; }   // tx ascending = code ascending
    }
    pval[(size_t)blockIdx.x * NROWS + row0 + tid] = best;
    pidx[(size_t)blockIdx.x * NROWS + row0 + tid] = bi;
  }
}

// Merge per-tile argmax partials (tiles ascending -> first-max ties).
__global__ __launch_bounds__(256)
void argmax_merge(const double* __restrict__ pval, const int* __restrict__ pidx,
                  int tiles, int* __restrict__ codes_out, int mod) {
  const int row = blockIdx.x * blockDim.x + threadIdx.x;
  if (row >= NROWS) return;
  double best = pval[row]; int bi = pidx[row];
  for (int t = 1; t < tiles; ++t) {
    double v = pval[(size_t)t * NROWS + row];
    if (v > best) { best = v; bi = pidx[(size_t)t * NROWS + row]; }
  }
  codes_out[(size_t)row * 3 + mod] = bi;
}

// logits[r] = dot(H[r], ksw), fp64 (sigmoid + ksb are monotone -> skipped).
__global__ __launch_bounds__(256)
void row_logits(const float* __restrict__ Hm, const float* __restrict__ ksw,
                double* __restrict__ logits) {
  const int row = blockIdx.x * 4 + (threadIdx.x >> 6);
  const int lane = threadIdx.x & 63;
  const float* r = Hm + (size_t)row * HID;
  double s = 0.0;
  for (int d = lane; d < HID; d += 64) s = fma((double)r[d], (double)ksw[d], s);
#pragma unroll
  for (int off = 32; off > 0; off >>= 1) s += __shfl_down(s, off, 64);
  if (lane == 0) logits[row] = s;
}

// =====================================================================
// Bitonic sort (desc by value, ties: lower index first == jax top_k),
// keeps top OUT per block. src_idx == nullptr -> iota (block-global).
// =====================================================================
template<int N>
__global__ __launch_bounds__(256)
void bitonic_topk(const double* __restrict__ src_val, const int* __restrict__ src_idx,
                  double* __restrict__ dst_val, int* __restrict__ dst_idx,
                  int out_per_block) {
  __shared__ double sv[N];
  __shared__ int    si[N];
  const int tid = threadIdx.x;
  const int base = blockIdx.x * N;
  for (int j = tid; j < N; j += 256) {
    sv[j] = src_val[base + j];
    si[j] = src_idx ? src_idx[base + j] : (base + j);
  }
  __syncthreads();
  for (int k = 2; k <= N; k <<= 1) {
    for (int j2 = k >> 1; j2 > 0; j2 >>= 1) {
      for (int i = tid; i < N; i += 256) {
        const int ixj = i ^ j2;
        if (ixj > i) {
          const double v1 = sv[i], v2 = sv[ixj];
          const int i1 = si[i], i2 = si[ixj];
          const bool bef = (v1 > v2) || (v1 == v2 && i1 < i2);
          const bool up = ((i & k) == 0);
          if (up ? !bef : bef) { sv[i] = v2; sv[ixj] = v1; si[i] = i2; si[ixj] = i1; }
        }
      }
      __syncthreads();
    }
  }
  for (int j = tid; j < out_per_block; j += 256) {
    dst_val[blockIdx.x * out_per_block + j] = sv[j];
    dst_idx[blockIdx.x * out_per_block + j] = si[j];
  }
}

// Write key_idx + gathered codes into d_out.
__global__ __launch_bounds__(256)
void finalize(const int* __restrict__ key_idx, int* __restrict__ out) {
  const int t = threadIdx.x;   // 0..255
  const int key = key_idx[t];
  out[NROWS * 3 + t] = key;
  int* sel = out + NROWS * 3 + TOPM;
  sel[t * 3 + 0] = out[(size_t)key * 3 + 0];
  sel[t * 3 + 1] = out[(size_t)key * 3 + 1];
  sel[t * 3 + 2] = out[(size_t)key * 3 + 2];
}

// =====================================================================
extern "C" void kernel_launch(void* const* d_in, const int* in_sizes, int n_in,
                              void* d_out, int out_size, void* d_ws, size_t ws_size,
                              hipStream_t stream) {
  const float* h0  = (const float*)d_in[0];
  const float* W1  = (const float*)d_in[1];
  const float* b1  = (const float*)d_in[2];
  const float* W2  = (const float*)d_in[3];
  const float* b2  = (const float*)d_in[4];
  const float* Wm  = (const float*)d_in[5];
  const float* bm  = (const float*)d_in[6];
  const float* Wt  = (const float*)d_in[7];
  const float* bt  = (const float*)d_in[8];
  const float* Wp  = (const float*)d_in[9];
  const float* bp  = (const float*)d_in[10];
  const float* Cm  = (const float*)d_in[11];
  const float* Ct  = (const float*)d_in[12];
  const float* Cp  = (const float*)d_in[13];
  const float* ksw = (const float*)d_in[14];
  int* out = (int*)d_out;

  char* ws = (char*)d_ws;
  size_t off = 0;
  float* bufZ = (float*)(ws + off); off += (size_t)NROWS * HID * 4;   // H1, then reused as Z
  float* bufH = (float*)(ws + off); off += (size_t)NROWS * HID * 4;   // H
  double* pval = (double*)(ws + off); off += (size_t)NROWS * 32 * 8;
  int*    pidx = (int*)(ws + off);    off += (size_t)NROWS * 32 * 4;
  double* invn = (double*)(ws + off); off += (size_t)CS * 8;
  double* logits = (double*)(ws + off); off += (size_t)NROWS * 8;
  double* cval = (double*)(ws + off); off += (size_t)8192 * 8;
  int*    cidx = (int*)(ws + off);    off += (size_t)8192 * 4;
  double* c2val = (double*)(ws + off); off += (size_t)2048 * 8;
  int*    c2idx = (int*)(ws + off);   off += (size_t)2048 * 4;

  const dim3 blk(256);

  // Encoder MLP (fp64 accumulation throughout)
  gemm_bias_act<true><<<dim3(HID / 64, NROWS / 64), blk, 0, stream>>>(
      h0, W1, b1, bufZ, NROWS, HID, DIN);                 // H1
  gemm_bias_act<true><<<dim3(HID / 64, NROWS / 64), blk, 0, stream>>>(
      bufZ, W2, b2, bufH, NROWS, HID, HID);               // H

  // Three modalities, sequential, reusing bufZ
  const float* Wmods[3] = {Wm, Wt, Wp};
  const float* bmods[3] = {bm, bt, bp};
  const float* Cmods[3] = {Cm, Ct, Cp};
  for (int mod = 0; mod < 3; ++mod) {
    gemm_bias_act<false><<<dim3(HID / 64, NROWS / 64), blk, 0, stream>>>(
        bufH, Wmods[mod], bmods[mod], bufZ, NROWS, HID, HID);   // z
    codebook_invnorm<<<dim3(CS / 4), blk, 0, stream>>>(Cmods[mod], invn, HID);
    dist_argmax<<<dim3(CS / 64, NROWS / 64), blk, 0, stream>>>(
        bufZ, Cmods[mod], invn, pval, pidx, HID);
    argmax_merge<<<dim3(NROWS / 256), blk, 0, stream>>>(pval, pidx, CS / 64, out, mod);
  }

  // Key-token scoring + top-256 (desc, stable ties) via 3-stage bitonic select
  row_logits<<<dim3(NROWS / 4), blk, 0, stream>>>(bufH, ksw, logits);
  bitonic_topk<1024><<<dim3(32), blk, 0, stream>>>(logits, nullptr, cval, cidx, 256);
  bitonic_topk<1024><<<dim3(8), blk, 0, stream>>>(cval, cidx, c2val, c2idx, 256);
  bitonic_topk<2048><<<dim3(1), blk, 0, stream>>>(c2val, c2idx, cval, cidx, 256);
  finalize<<<dim3(1), blk, 0, stream>>>(cidx, out);
}

// Round 2
// 14989.137 us; speedup vs baseline: 1.4500x; 1.4500x over previous
//
#include <hip/hip_runtime.h>
#include <cstdint>
#include <cstddef>

constexpr int NROWS = 32768;
constexpr int DIN   = 2048;
constexpr int HID   = 1024;
constexpr int CS    = 2048;
constexpr int TOPM  = 256;
constexpr float  TH_SIM = 1e-4f;   // cosine-margin threshold for contested rows
constexpr double TH_LOG = 1e-3;    // logit band for top-k candidates
constexpr int CANDMAX = 2048;

// =====================================================================
// Phase A: fp32 128x128 GEMM, BK=16, 256 threads, 8x8 per thread.
// C = act(A[M,K] @ B[K,N] + bias). Row-major. M%128==0, N%128==0, K%16==0.
// =====================================================================
template<bool RELU>
__global__ __launch_bounds__(256)
void gemm_f32(const float* __restrict__ A, const float* __restrict__ B,
              const float* __restrict__ bias, float* __restrict__ C,
              int N, int K) {
  constexpr int BM = 128, BN = 128, BK = 16;
  __shared__ float As[BK][BM + 4];   // +4 keeps float4 rows 16B-aligned
  __shared__ float Bs[BK][BN + 4];
  const int tid = threadIdx.x;
  const int tx = tid & 15, ty = tid >> 4;
  const int row0 = blockIdx.y * BM, col0 = blockIdx.x * BN;
  const int ar = tid >> 1, akc = (tid & 1) * 8;
  const int bkr = tid >> 4, bcc = (tid & 15) * 8;
  const float* Ap = A + (size_t)(row0 + ar) * K + akc;
  const float* Bp = B + (size_t)bkr * N + col0 + bcc;
  float acc[8][8] = {};
  for (int k0 = 0; k0 < K; k0 += BK) {
    float4 a0 = *(const float4*)(Ap + k0);
    float4 a1 = *(const float4*)(Ap + k0 + 4);
    float4 b0 = *(const float4*)(Bp + (size_t)k0 * N);
    float4 b1 = *(const float4*)(Bp + (size_t)k0 * N + 4);
    if (k0) __syncthreads();
    As[akc + 0][ar] = a0.x; As[akc + 1][ar] = a0.y;
    As[akc + 2][ar] = a0.z; As[akc + 3][ar] = a0.w;
    As[akc + 4][ar] = a1.x; As[akc + 5][ar] = a1.y;
    As[akc + 6][ar] = a1.z; As[akc + 7][ar] = a1.w;
    *(float4*)&Bs[bkr][bcc]     = b0;
    *(float4*)&Bs[bkr][bcc + 4] = b1;
    __syncthreads();
#pragma unroll
    for (int kk = 0; kk < BK; ++kk) {
      float a[8], b[8];
      *(float4*)&a[0] = *(const float4*)&As[kk][ty * 8];
      *(float4*)&a[4] = *(const float4*)&As[kk][ty * 8 + 4];
      *(float4*)&b[0] = *(const float4*)&Bs[kk][tx * 8];
      *(float4*)&b[4] = *(const float4*)&Bs[kk][tx * 8 + 4];
#pragma unroll
      for (int i = 0; i < 8; ++i)
#pragma unroll
        for (int j = 0; j < 8; ++j)
          acc[i][j] = fmaf(a[i], b[j], acc[i][j]);
    }
  }
  float bv[8];
#pragma unroll
  for (int j = 0; j < 8; ++j) bv[j] = bias[col0 + tx * 8 + j];
#pragma unroll
  for (int i = 0; i < 8; ++i) {
    const int r = row0 + ty * 8 + i;
    float o[8];
#pragma unroll
    for (int j = 0; j < 8; ++j) {
      float v = acc[i][j] + bv[j];
      o[j] = RELU ? (v > 0.f ? v : 0.f) : v;
    }
    *(float4*)(C + (size_t)r * N + col0 + tx * 8)     = *(float4*)&o[0];
    *(float4*)(C + (size_t)r * N + col0 + tx * 8 + 4) = *(float4*)&o[4];
  }
}

// =====================================================================
// Phase A dist: 128 rows x 128 codes tile; sims = dot(Z,Cb)*invn_f[c];
// per-row/tile best + second-best + best idx partials.
// =====================================================================
__global__ __launch_bounds__(256)
void gemm_dist(const float* __restrict__ Z, const float* __restrict__ Cb,
               const float* __restrict__ invF,
               float* __restrict__ pb, float* __restrict__ ps, int* __restrict__ pi,
               int K) {
  constexpr int BM = 128, BN = 128, BK = 16;
  __shared__ float As[BK][BM + 4];
  __shared__ float Bs[BK][BN + 4];
  __shared__ float rb[BM][17];
  __shared__ float rs[BM][17];
  __shared__ int   ri[BM][17];
  const int tid = threadIdx.x;
  const int tx = tid & 15, ty = tid >> 4;
  const int row0 = blockIdx.y * BM, col0 = blockIdx.x * BN;
  const int ar = tid >> 1, akc = (tid & 1) * 8;
  const float* Ap = Z  + (size_t)(row0 + ar) * K + akc;
  const float* Cp = Cb + (size_t)(col0 + ar) * K + akc;
  float acc[8][8] = {};
  for (int k0 = 0; k0 < K; k0 += BK) {
    float4 a0 = *(const float4*)(Ap + k0);
    float4 a1 = *(const float4*)(Ap + k0 + 4);
    float4 c0 = *(const float4*)(Cp + k0);
    float4 c1 = *(const float4*)(Cp + k0 + 4);
    if (k0) __syncthreads();
    As[akc + 0][ar] = a0.x; As[akc + 1][ar] = a0.y;
    As[akc + 2][ar] = a0.z; As[akc + 3][ar] = a0.w;
    As[akc + 4][ar] = a1.x; As[akc + 5][ar] = a1.y;
    As[akc + 6][ar] = a1.z; As[akc + 7][ar] = a1.w;
    Bs[akc + 0][ar] = c0.x; Bs[akc + 1][ar] = c0.y;
    Bs[akc + 2][ar] = c0.z; Bs[akc + 3][ar] = c0.w;
    Bs[akc + 4][ar] = c1.x; Bs[akc + 5][ar] = c1.y;
    Bs[akc + 6][ar] = c1.z; Bs[akc + 7][ar] = c1.w;
    __syncthreads();
#pragma unroll
    for (int kk = 0; kk < BK; ++kk) {
      float a[8], b[8];
      *(float4*)&a[0] = *(const float4*)&As[kk][ty * 8];
      *(float4*)&a[4] = *(const float4*)&As[kk][ty * 8 + 4];
      *(float4*)&b[0] = *(const float4*)&Bs[kk][tx * 8];
      *(float4*)&b[4] = *(const float4*)&Bs[kk][tx * 8 + 4];
#pragma unroll
      for (int i = 0; i < 8; ++i)
#pragma unroll
        for (int j = 0; j < 8; ++j)
          acc[i][j] = fmaf(a[i], b[j], acc[i][j]);
    }
  }
  float inv[8];
#pragma unroll
  for (int j = 0; j < 8; ++j) inv[j] = invF[col0 + tx * 8 + j];
  __syncthreads();
#pragma unroll
  for (int i = 0; i < 8; ++i) {
    float b = acc[i][0] * inv[0], s = -3.4e38f;
    int bi = col0 + tx * 8;
#pragma unroll
    for (int j = 1; j < 8; ++j) {
      float v = acc[i][j] * inv[j];
      if (v > b) { s = b; b = v; bi = col0 + tx * 8 + j; }
      else       { s = fmaxf(s, v); }
    }
    rb[ty * 8 + i][tx] = b; rs[ty * 8 + i][tx] = s; ri[ty * 8 + i][tx] = bi;
  }
  __syncthreads();
  if (tid < BM) {
    float b = rb[tid][0], s = rs[tid][0];
    int bi = ri[tid][0];
    for (int t = 1; t < 16; ++t) {
      float b2 = rb[tid][t], s2 = rs[tid][t];
      if (b2 > b) { s = fmaxf(b, s2); b = b2; bi = ri[tid][t]; }
      else        { s = fmaxf(s, b2); }
    }
    const size_t o = (size_t)blockIdx.x * NROWS + row0 + tid;
    pb[o] = b; ps[o] = s; pi[o] = bi;
  }
}

__global__ __launch_bounds__(256)
void merge_dist(const float* __restrict__ pb, const float* __restrict__ ps,
                const int* __restrict__ pi, const float* __restrict__ zinv,
                int* __restrict__ codes, int* __restrict__ flags, int mod) {
  const int r = blockIdx.x * 256 + threadIdx.x;
  if (r >= NROWS) return;
  float b = pb[r], s = ps[r]; int bi = pi[r];
  for (int t = 1; t < 16; ++t) {
    float b2 = pb[(size_t)t * NROWS + r], s2 = ps[(size_t)t * NROWS + r];
    if (b2 > b) { s = fmaxf(b, s2); b = b2; bi = pi[(size_t)t * NROWS + r]; }
    else        { s = fmaxf(s, b2); }
  }
  codes[(size_t)r * 3 + mod] = bi;
  if ((b - s) * zinv[r] < TH_SIM) flags[r] |= (1 << mod);
}

// invn: fp64 compute; dual fp64/fp32 output. 4 rows (waves) per block.
__global__ __launch_bounds__(256)
void codebook_invnorm(const float* __restrict__ Cb, double* __restrict__ invD,
                      float* __restrict__ invF, int K) {
  const int code = blockIdx.x * 4 + (threadIdx.x >> 6);
  const int lane = threadIdx.x & 63;
  const float* r = Cb + (size_t)code * K;
  double s = 0.0;
  for (int d = lane; d < K; d += 64) { double v = (double)r[d]; s = fma(v, v, s); }
#pragma unroll
  for (int off = 32; off > 0; off >>= 1) s += __shfl_down(s, off, 64);
  if (lane == 0) { double iv = 1.0 / sqrt(s + 1e-12); invD[code] = iv; invF[code] = (float)iv; }
}

__global__ __launch_bounds__(256)
void zinv_rows(const float* __restrict__ Z, float* __restrict__ zinv) {
  const int row = blockIdx.x * 4 + (threadIdx.x >> 6);
  const int lane = threadIdx.x & 63;
  const float* r = Z + (size_t)row * HID;
  float s = 0.f;
  for (int d = lane; d < HID; d += 64) { float v = r[d]; s = fmaf(v, v, s); }
#pragma unroll
  for (int off = 32; off > 0; off >>= 1) s += __shfl_down(s, off, 64);
  if (lane == 0) zinv[row] = rsqrtf(s + 1e-12f);
}

// logits (fp64 acc over fp32 H) - used for candidate banding only.
__global__ __launch_bounds__(256)
void row_logits(const float* __restrict__ Hm, const float* __restrict__ ksw,
                double* __restrict__ logits) {
  const int row = blockIdx.x * 4 + (threadIdx.x >> 6);
  const int lane = threadIdx.x & 63;
  const float* r = Hm + (size_t)row * HID;
  double s = 0.0;
  for (int d = lane; d < HID; d += 64) s = fma((double)r[d], (double)ksw[d], s);
#pragma unroll
  for (int off = 32; off > 0; off >>= 1) s += __shfl_down(s, off, 64);
  if (lane == 0) logits[row] = s;
}

// Bitonic top-k (desc, tie -> lower index), as validated in R1.
template<int N>
__global__ __launch_bounds__(256)
void bitonic_topk(const double* __restrict__ src_val, const int* __restrict__ src_idx,
                  double* __restrict__ dst_val, int* __restrict__ dst_idx,
                  int out_per_block) {
  __shared__ double sv[N];
  __shared__ int    si[N];
  const int tid = threadIdx.x;
  const int base = blockIdx.x * N;
  for (int j = tid; j < N; j += 256) {
    sv[j] = src_val[base + j];
    si[j] = src_idx ? src_idx[base + j] : (base + j);
  }
  __syncthreads();
  for (int k = 2; k <= N; k <<= 1) {
    for (int j2 = k >> 1; j2 > 0; j2 >>= 1) {
      for (int i = tid; i < N; i += 256) {
        const int ixj = i ^ j2;
        if (ixj > i) {
          const double v1 = sv[i], v2 = sv[ixj];
          const int i1 = si[i], i2 = si[ixj];
          const bool bef = (v1 > v2) || (v1 == v2 && i1 < i2);
          const bool up = ((i & k) == 0);
          if (up ? !bef : bef) { sv[i] = v2; sv[ixj] = v1; si[i] = i2; si[ixj] = i1; }
        }
      }
      __syncthreads();
    }
  }
  for (int j = tid; j < out_per_block; j += 256) {
    dst_val[blockIdx.x * out_per_block + j] = sv[j];
    dst_idx[blockIdx.x * out_per_block + j] = si[j];
  }
}

// =====================================================================
// Contested-set machinery
// =====================================================================
__global__ __launch_bounds__(256)
void zero_init(int* __restrict__ flags, int* __restrict__ rowpos, int* __restrict__ counters) {
  const int r = blockIdx.x * 256 + threadIdx.x;
  if (r < NROWS) { flags[r] = 0; rowpos[r] = 0; }
  if (r < 2) counters[r] = 0;
}

__global__ void cutoff_kernel(const double* __restrict__ c3val, double* __restrict__ cut) {
  if (threadIdx.x == 0) cut[0] = c3val[255] - TH_LOG;
}

__global__ __launch_bounds__(256)
void cand_flag(const double* __restrict__ logits, const double* __restrict__ cut,
               int* __restrict__ flags, int* __restrict__ cand, int* __restrict__ counters) {
  const int r = blockIdx.x * 256 + threadIdx.x;
  if (r >= NROWS) return;
  if (logits[r] >= cut[0]) {
    flags[r] |= 8;
    const int p = atomicAdd(&counters[1], 1);
    if (p < CANDMAX) cand[p] = r;
  }
}

__global__ __launch_bounds__(256)
void build_list(const int* __restrict__ flags, int* __restrict__ list,
                int* __restrict__ rowpos, int* __restrict__ counters, int cap) {
  const int r = blockIdx.x * 256 + threadIdx.x;
  if (r >= NROWS) return;
  if (flags[r]) {
    const int p = atomicAdd(&counters[0], 1);
    if (p < cap) { list[p] = r; rowpos[r] = p; }
  }
}

// =====================================================================
// Exact fp64 recompute on gathered contested rows. 64x64 tile, BK=16.
// =====================================================================
template<bool RELU, bool GATHER>
__global__ __launch_bounds__(256)
void gemm_rows_f64(const int* __restrict__ list, const int* __restrict__ countp, int cap,
                   const float* __restrict__ Af32, const double* __restrict__ Ad,
                   const float* __restrict__ B, const float* __restrict__ bias,
                   double* __restrict__ Cd, int K) {
  constexpr int BM = 64, BN = 64, BK = 16;
  __shared__ double As[BK][BM + 1];
  __shared__ double Bs[BK][BN + 1];
  int cnt = *countp; cnt = cnt < cap ? cnt : cap;
  const int row0 = blockIdx.y * BM;
  if (row0 >= cnt) return;
  const int col0 = blockIdx.x * BN;
  const int tid = threadIdx.x;
  const int tx = tid & 15, ty = tid >> 4;
  const int ar = tid >> 2, ak = (tid & 3) * 4;
  const int bk = tid >> 4, bc = (tid & 15) * 4;
  const int pa = (row0 + ar < cnt) ? (row0 + ar) : 0;
  const float*  af = nullptr;
  const double* ad = nullptr;
  if (GATHER) af = Af32 + (size_t)list[pa] * K;
  else        ad = Ad + (size_t)pa * HID;
  double acc[4][4] = {};
  for (int k0 = 0; k0 < K; k0 += BK) {
    if (GATHER) {
      const float4 v = *(const float4*)(af + k0 + ak);
      As[ak + 0][ar] = (double)v.x; As[ak + 1][ar] = (double)v.y;
      As[ak + 2][ar] = (double)v.z; As[ak + 3][ar] = (double)v.w;
    } else {
      As[ak + 0][ar] = ad[k0 + ak + 0]; As[ak + 1][ar] = ad[k0 + ak + 1];
      As[ak + 2][ar] = ad[k0 + ak + 2]; As[ak + 3][ar] = ad[k0 + ak + 3];
    }
    const float4 bv = *(const float4*)(B + (size_t)(k0 + bk) * HID + col0 + bc);
    Bs[bk][bc + 0] = (double)bv.x; Bs[bk][bc + 1] = (double)bv.y;
    Bs[bk][bc + 2] = (double)bv.z; Bs[bk][bc + 3] = (double)bv.w;
    __syncthreads();
#pragma unroll
    for (int kk = 0; kk < BK; ++kk) {
      double a0 = As[kk][ty * 4 + 0], a1 = As[kk][ty * 4 + 1];
      double a2 = As[kk][ty * 4 + 2], a3 = As[kk][ty * 4 + 3];
      double b0 = Bs[kk][tx * 4 + 0], b1 = Bs[kk][tx * 4 + 1];
      double b2 = Bs[kk][tx * 4 + 2], b3 = Bs[kk][tx * 4 + 3];
      acc[0][0] = fma(a0, b0, acc[0][0]); acc[0][1] = fma(a0, b1, acc[0][1]);
      acc[0][2] = fma(a0, b2, acc[0][2]); acc[0][3] = fma(a0, b3, acc[0][3]);
      acc[1][0] = fma(a1, b0, acc[1][0]); acc[1][1] = fma(a1, b1, acc[1][1]);
      acc[1][2] = fma(a1, b2, acc[1][2]); acc[1][3] = fma(a1, b3, acc[1][3]);
      acc[2][0] = fma(a2, b0, acc[2][0]); acc[2][1] = fma(a2, b1, acc[2][1]);
      acc[2][2] = fma(a2, b2, acc[2][2]); acc[2][3] = fma(a2, b3, acc[2][3]);
      acc[3][0] = fma(a3, b0, acc[3][0]); acc[3][1] = fma(a3, b1, acc[3][1]);
      acc[3][2] = fma(a3, b2, acc[3][2]); acc[3][3] = fma(a3, b3, acc[3][3]);
    }
    __syncthreads();
  }
#pragma unroll
  for (int i = 0; i < 4; ++i) {
    const int p = row0 + ty * 4 + i;
    if (p >= cnt) continue;
#pragma unroll
    for (int j = 0; j < 4; ++j) {
      double v = acc[i][j] + (double)bias[col0 + tx * 4 + j];
      if (RELU) v = v > 0.0 ? v : 0.0;
      Cd[(size_t)p * HID + col0 + tx * 4 + j] = v;
    }
  }
}

// Exact dist: 16 rows x 64 codes per block, fp64, partial argmax per tile.
__global__ __launch_bounds__(256)
void dist_exact(const int* __restrict__ countp, int cap,
                const double* __restrict__ zd, const float* __restrict__ Cb,
                const double* __restrict__ invD,
                double* __restrict__ ebest, int* __restrict__ eidx) {
  __shared__ double Zs[16][33];
  __shared__ double Cs[64][33];
  __shared__ double rb[16][17];
  __shared__ int    ri[16][17];
  int cnt = *countp; cnt = cnt < cap ? cnt : cap;
  const int p0 = blockIdx.y * 16;
  if (p0 >= cnt) return;
  const int c0 = blockIdx.x * 64;
  const int tid = threadIdx.x;
  const int row = tid >> 4, cg = (tid & 15) * 4;
  double acc[4] = {};
  const int zr = tid & 15, zk = tid >> 4;
  const int pz = (p0 + zr < cnt) ? (p0 + zr) : p0;
  const int cc = tid & 63, kb = (tid >> 6) * 8;
  for (int k0 = 0; k0 < HID; k0 += 32) {
    const double v0 = zd[(size_t)pz * HID + k0 + zk];
    const double v1 = zd[(size_t)pz * HID + k0 + zk + 16];
    const float4 f0 = *(const float4*)(Cb + (size_t)(c0 + cc) * HID + k0 + kb);
    const float4 f1 = *(const float4*)(Cb + (size_t)(c0 + cc) * HID + k0 + kb + 4);
    if (k0) __syncthreads();
    Zs[zr][zk] = v0; Zs[zr][zk + 16] = v1;
    Cs[cc][kb + 0] = (double)f0.x; Cs[cc][kb + 1] = (double)f0.y;
    Cs[cc][kb + 2] = (double)f0.z; Cs[cc][kb + 3] = (double)f0.w;
    Cs[cc][kb + 4] = (double)f1.x; Cs[cc][kb + 5] = (double)f1.y;
    Cs[cc][kb + 6] = (double)f1.z; Cs[cc][kb + 7] = (double)f1.w;
    __syncthreads();
#pragma unroll 8
    for (int kk = 0; kk < 32; ++kk) {
      const double a = Zs[row][kk];
      acc[0] = fma(a, Cs[cg + 0][kk], acc[0]);
      acc[1] = fma(a, Cs[cg + 1][kk], acc[1]);
      acc[2] = fma(a, Cs[cg + 2][kk], acc[2]);
      acc[3] = fma(a, Cs[cg + 3][kk], acc[3]);
    }
  }
  double best = acc[0] * invD[c0 + cg]; int bi = c0 + cg;
#pragma unroll
  for (int c = 1; c < 4; ++c) {
    const double v = acc[c] * invD[c0 + cg + c];
    if (v > best) { best = v; bi = c0 + cg + c; }
  }
  __syncthreads();
  rb[row][tid & 15] = best; ri[row][tid & 15] = bi;
  __syncthreads();
  if (tid < 16) {
    double b = rb[tid][0]; int i0 = ri[tid][0];
    for (int t = 1; t < 16; ++t) {
      const double v = rb[tid][t];
      if (v > b) { b = v; i0 = ri[tid][t]; }
    }
    if (p0 + tid < cnt) {
      ebest[(size_t)blockIdx.x * cap + p0 + tid] = b;
      eidx [(size_t)blockIdx.x * cap + p0 + tid] = i0;
    }
  }
}

__global__ __launch_bounds__(256)
void dist_exact_merge(const int* __restrict__ countp, int cap, const int* __restrict__ list,
                      const double* __restrict__ ebest, const int* __restrict__ eidx,
                      int* __restrict__ codes, int mod) {
  int cnt = *countp; cnt = cnt < cap ? cnt : cap;
  const int p = blockIdx.x * 256 + threadIdx.x;
  if (p >= cnt) return;
  double b = ebest[p]; int bi = eidx[p];
  for (int t = 1; t < 32; ++t) {
    const double v = ebest[(size_t)t * cap + p];
    if (v > b) { b = v; bi = eidx[(size_t)t * cap + p]; }
  }
  codes[(size_t)list[p] * 3 + mod] = bi;
}

__global__ __launch_bounds__(256)
void logits_exact(const int* __restrict__ candcountp, const int* __restrict__ cand,
                  const int* __restrict__ rowpos, const double* __restrict__ Hd,
                  const float* __restrict__ ksw,
                  double* __restrict__ cvalE, int* __restrict__ cidxE) {
  const int i = blockIdx.x * 4 + (threadIdx.x >> 6);
  const int lane = threadIdx.x & 63;
  int cc = *candcountp; cc = cc < CANDMAX ? cc : CANDMAX;
  if (i >= CANDMAX) return;
  if (i < cc) {
    const int r = cand[i];
    const double* h = Hd + (size_t)rowpos[r] * HID;
    double s = 0.0;
    for (int d = lane; d < HID; d += 64) s = fma(h[d], (double)ksw[d], s);
#pragma unroll
    for (int off = 32; off > 0; off >>= 1) s += __shfl_down(s, off, 64);
    if (lane == 0) { cvalE[i] = s; cidxE[i] = r; }
  } else if (lane == 0) {
    cvalE[i] = -1e300; cidxE[i] = 0x7FFFFFFF;
  }
}

__global__ void finalize2(const int* __restrict__ kidx, int* __restrict__ out) {
  const int t = threadIdx.x;
  const int k = kidx[t];
  out[NROWS * 3 + t] = k;
  int* sel = out + NROWS * 3 + TOPM;
  sel[t * 3 + 0] = out[(size_t)k * 3 + 0];
  sel[t * 3 + 1] = out[(size_t)k * 3 + 1];
  sel[t * 3 + 2] = out[(size_t)k * 3 + 2];
}

// =====================================================================
extern "C" void kernel_launch(void* const* d_in, const int* in_sizes, int n_in,
                              void* d_out, int out_size, void* d_ws, size_t ws_size,
                              hipStream_t stream) {
  const float* h0  = (const float*)d_in[0];
  const float* W1  = (const float*)d_in[1];
  const float* b1  = (const float*)d_in[2];
  const float* W2  = (const float*)d_in[3];
  const float* b2  = (const float*)d_in[4];
  const float* Wm  = (const float*)d_in[5];
  const float* bm  = (const float*)d_in[6];
  const float* Wt  = (const float*)d_in[7];
  const float* bt  = (const float*)d_in[8];
  const float* Wp  = (const float*)d_in[9];
  const float* bp  = (const float*)d_in[10];
  const float* Cm  = (const float*)d_in[11];
  const float* Ct  = (const float*)d_in[12];
  const float* Cp  = (const float*)d_in[13];
  const float* ksw = (const float*)d_in[14];
  int* out = (int*)d_out;

  // cap for contested rows, sized from ws
  size_t fixed = (size_t)NROWS * HID * 4 * 2      // bufA, bufH
               + (size_t)16 * NROWS * 12          // pb, ps, pi
               + (size_t)NROWS * 8                // logits
               + (size_t)NROWS * 4 * 3            // zinv, flags, rowpos
               + (size_t)(8192 + 2048 + 256 + CANDMAX + 256) * 12
               + (size_t)3 * CS * 12 + (4 << 20); // invn + slack
  long long rem = (long long)ws_size - (long long)fixed;
  int cap = (int)(rem / 16800);
  cap = cap < 1024 ? 1024 : (cap > 6144 ? 6144 : cap);
  cap &= ~63;

  char* ws = (char*)d_ws;
  size_t off = 0;
  auto alloc = [&](size_t bytes) { void* p = ws + off; off = (off + bytes + 255) & ~(size_t)255; return p; };
  double* Hd     = (double*)alloc((size_t)cap * HID * 8);
  double* H1d    = (double*)alloc((size_t)cap * HID * 8);   // also reused as zd
  double* ebest  = (double*)alloc((size_t)32 * cap * 8);
  double* logits = (double*)alloc((size_t)NROWS * 8);
  double* cvalA  = (double*)alloc(8192 * 8);
  double* c2val  = (double*)alloc(2048 * 8);
  double* c3val  = (double*)alloc(256 * 8);
  double* cvalE  = (double*)alloc(CANDMAX * 8);
  double* kval   = (double*)alloc(256 * 8);
  double* invD   = (double*)alloc((size_t)3 * CS * 8);
  double* cut    = (double*)alloc(256);
  float* bufA    = (float*)alloc((size_t)NROWS * HID * 4);  // H1, then Z
  float* bufH    = (float*)alloc((size_t)NROWS * HID * 4);
  float* pb      = (float*)alloc((size_t)16 * NROWS * 4);
  float* ps      = (float*)alloc((size_t)16 * NROWS * 4);
  float* invF    = (float*)alloc((size_t)3 * CS * 4);
  float* zinv    = (float*)alloc((size_t)NROWS * 4);
  int* pi        = (int*)alloc((size_t)16 * NROWS * 4);
  int* eidx      = (int*)alloc((size_t)32 * cap * 4);
  int* cidxA     = (int*)alloc(8192 * 4);
  int* c2idx     = (int*)alloc(2048 * 4);
  int* c3idx     = (int*)alloc(256 * 4);
  int* cidxE     = (int*)alloc(CANDMAX * 4);
  int* kidx      = (int*)alloc(256 * 4);
  int* flags     = (int*)alloc((size_t)NROWS * 4);
  int* rowpos    = (int*)alloc((size_t)NROWS * 4);
  int* list      = (int*)alloc((size_t)cap * 4);
  int* cand      = (int*)alloc(CANDMAX * 4);
  int* counters  = (int*)alloc(64);

  const dim3 blk(256);
  const float* Wmods[3] = {Wm, Wt, Wp};
  const float* bmods[3] = {bm, bt, bp};
  const float* Cmods[3] = {Cm, Ct, Cp};

  zero_init<<<dim3(NROWS / 256), blk, 0, stream>>>(flags, rowpos, counters);

  // ---- Phase A: fp32 ----
  gemm_f32<true><<<dim3(HID / 128, NROWS / 128), blk, 0, stream>>>(h0, W1, b1, bufA, HID, DIN);
  gemm_f32<true><<<dim3(HID / 128, NROWS / 128), blk, 0, stream>>>(bufA, W2, b2, bufH, HID, HID);
  row_logits<<<dim3(NROWS / 4), blk, 0, stream>>>(bufH, ksw, logits);

  for (int mod = 0; mod < 3; ++mod) {
    gemm_f32<false><<<dim3(HID / 128, NROWS / 128), blk, 0, stream>>>(
        bufH, Wmods[mod], bmods[mod], bufA, HID, HID);
    codebook_invnorm<<<dim3(CS / 4), blk, 0, stream>>>(Cmods[mod], invD + mod * CS, invF + mod * CS, HID);
    zinv_rows<<<dim3(NROWS / 4), blk, 0, stream>>>(bufA, zinv);
    gemm_dist<<<dim3(CS / 128, NROWS / 128), blk, 0, stream>>>(
        bufA, Cmods[mod], invF + mod * CS, pb, ps, pi, HID);
    merge_dist<<<dim3(NROWS / 256), blk, 0, stream>>>(pb, ps, pi, zinv, out, flags, mod);
  }

  // ---- approx top-k banding ----
  bitonic_topk<1024><<<dim3(32), blk, 0, stream>>>(logits, nullptr, cvalA, cidxA, 256);
  bitonic_topk<1024><<<dim3(8), blk, 0, stream>>>(cvalA, cidxA, c2val, c2idx, 256);
  bitonic_topk<2048><<<dim3(1), blk, 0, stream>>>(c2val, c2idx, c3val, c3idx, 256);
  cutoff_kernel<<<dim3(1), dim3(64), 0, stream>>>(c3val, cut);
  cand_flag<<<dim3(NROWS / 256), blk, 0, stream>>>(logits, cut, flags, cand, counters);
  build_list<<<dim3(NROWS / 256), blk, 0, stream>>>(flags, list, rowpos, counters, cap);

  // ---- exact fp64 refine of contested rows ----
  gemm_rows_f64<true, true><<<dim3(HID / 64, cap / 64), blk, 0, stream>>>(
      list, counters, cap, h0, nullptr, W1, b1, H1d, DIN);
  gemm_rows_f64<true, false><<<dim3(HID / 64, cap / 64), blk, 0, stream>>>(
      list, counters, cap, nullptr, H1d, W2, b2, Hd, HID);
  for (int mod = 0; mod < 3; ++mod) {
    gemm_rows_f64<false, false><<<dim3(HID / 64, cap / 64), blk, 0, stream>>>(
        list, counters, cap, nullptr, Hd, Wmods[mod], bmods[mod], H1d, HID);  // H1d = zd
    dist_exact<<<dim3(CS / 64, cap / 16), blk, 0, stream>>>(
        counters, cap, H1d, Cmods[mod], invD + mod * CS, ebest, eidx);
    dist_exact_merge<<<dim3((cap + 255) / 256), blk, 0, stream>>>(
        counters, cap, list, ebest, eidx, out, mod);
  }

  // ---- exact top-256 ----
  logits_exact<<<dim3(CANDMAX / 4), blk, 0, stream>>>(counters + 1, cand, rowpos, Hd, ksw, cvalE, cidxE);
  bitonic_topk<2048><<<dim3(1), blk, 0, stream>>>(cvalE, cidxE, kval, kidx, 256);
  finalize2<<<dim3(1), blk, 0, stream>>>(kidx, out);
}

// Round 3
// 11093.528 us; speedup vs baseline: 1.9591x; 1.3512x over previous
//
#include <hip/hip_runtime.h>
#include <cstdint>
#include <cstddef>

typedef unsigned short u16;
typedef unsigned int u32;
typedef __attribute__((ext_vector_type(8))) short short8;
typedef __attribute__((ext_vector_type(4))) float f32x4;

constexpr int NROWS = 32768;
constexpr int DIN   = 2048;
constexpr int HID   = 1024;
constexpr int CS    = 2048;
constexpr int TOPM  = 256;
constexpr float  TH_SIM = 2e-4f;   // cosine-margin threshold (bf16x2 dist err ~1e-5)
constexpr double TH_LOG = 1e-3;    // logit band for top-k candidates
constexpr int CANDMAX = 2048;

// ---------------------------------------------------------------------
// bf16 split helpers
// ---------------------------------------------------------------------
__device__ __forceinline__ u16 f2bf(float x) {
  u32 u = __float_as_uint(x);
  u += 0x7FFF + ((u >> 16) & 1);          // RNE
  return (u16)(u >> 16);
}
__device__ __forceinline__ float bf2f(u16 h) { return __uint_as_float(((u32)h) << 16); }
__device__ __forceinline__ void split3(float x, u16& h, u16& m, u16& l) {
  h = f2bf(x); float r = x - bf2f(h);
  m = f2bf(r); float r2 = r - bf2f(m);
  l = f2bf(r2);
}

__device__ __forceinline__ void async16(const u16* gp, const u16* lp) {
  __builtin_amdgcn_global_load_lds(
      (const __attribute__((address_space(1))) unsigned int*)gp,
      (__attribute__((address_space(3))) unsigned int*)(unsigned int)(uintptr_t)lp,
      16, 0, 0);
}

// =====================================================================
// gemm3: C = A(fp32, split-in-staging, bf16xNS) @ B(pre-split planes)^T
// 128x128 tile, BK=32, 4 waves (2x2), wave tile 64x64, 4x4 MFMA 16x16x32.
// MODE 0: relu(acc+bias)->Cf ; MODE 1: acc+bias->Cf ; MODE 2: dist argmax
// =====================================================================
template<int MODE, int NS>
__global__ __launch_bounds__(256)
void gemm3(const float* __restrict__ Af,
           const u16* __restrict__ B0, const u16* __restrict__ B1, const u16* __restrict__ B2,
           const float* __restrict__ bias, float* __restrict__ Cf,
           const float* __restrict__ invF,
           float* __restrict__ pb, float* __restrict__ ps, int* __restrict__ pi,
           int N, int K) {
  __shared__ u16 smem[NS * 2 * 4096];   // A: NS x 8KB, B: NS x 8KB
  __shared__ float sb_b[128][2];
  __shared__ float sb_s[128][2];
  __shared__ int   sb_i[128][2];

  const int tid = threadIdx.x, lane = tid & 63, wv = tid >> 6;
  const int wy = wv >> 1, wx = wv & 1;
  const int m15 = lane & 15, q4 = lane >> 4;
  const int row0 = blockIdx.y * 128, col0 = blockIdx.x * 128;
  const u16* Bp[3] = {B0, B1, B2};

  f32x4 acc[4][4] = {};

  // A staging role: thread t covers row r_=t>>1, k-half hf=t&1 (16 floats)
  const int r_ = tid >> 1, hf = tid & 1;
  const float* aptr = Af + (size_t)(row0 + r_) * K + hf * 16;
  const int swA = (r_ >> 1) & 3;

  // B staging role: per-wave NS*2 dma instrs
  const int brloc = lane >> 2;                      // 0..15 within 16-row group
  const int bq = (lane & 3) ^ ((lane >> 3) & 3);    // swizzled source chunk

  // frag read offsets (ushort units)
  int ra[4], rb[4];
#pragma unroll
  for (int mt = 0; mt < 4; ++mt) {
    int r = wy * 64 + mt * 16 + m15;
    ra[mt] = r * 32 + ((q4 ^ ((r >> 1) & 3)) * 8);
  }
#pragma unroll
  for (int nt = 0; nt < 4; ++nt) {
    int n = wx * 64 + nt * 16 + m15;
    rb[nt] = n * 32 + ((q4 ^ ((n >> 1) & 3)) * 8);
  }

  f32x4 pf[4];
#pragma unroll
  for (int i = 0; i < 4; ++i) pf[i] = *(const f32x4*)(aptr + 4 * i);

  for (int k0 = 0; k0 < K; k0 += 32) {
    if (k0) __syncthreads();
    // ---- A: split pf -> ds_write (swizzled slots) ----
#pragma unroll
    for (int c = 0; c < 2; ++c) {
      const int q = 2 * hf + c;
      const int slot = q ^ swA;
      float f[8];
#pragma unroll
      for (int j = 0; j < 4; ++j) { f[j] = pf[2 * c][j]; f[4 + j] = pf[2 * c + 1][j]; }
      u16 hh[8], mm[8], ll[8];
#pragma unroll
      for (int j = 0; j < 8; ++j) split3(f[j], hh[j], mm[j], ll[j]);
      const int base = r_ * 32 + slot * 8;
      short8 v0, v1, v2;
#pragma unroll
      for (int j = 0; j < 8; ++j) { v0[j] = (short)hh[j]; v1[j] = (short)mm[j]; v2[j] = (short)ll[j]; }
      *(short8*)&smem[base] = v0;
      if (NS > 1) *(short8*)&smem[4096 + base] = v1;
      if (NS > 2) *(short8*)&smem[8192 + base] = v2;
    }
    // ---- B: async global->LDS, swizzle via source-chunk selection ----
#pragma unroll
    for (int i = 0; i < NS * 2; ++i) {
      const int idx = wv * (NS * 2) + i;
      const int s = idx >> 3, j = idx & 7;
      const u16* gp = Bp[s] + (size_t)(col0 + 16 * j + brloc) * K + k0 + bq * 8;
      async16(gp, &smem[NS * 4096 + s * 4096 + j * 512]);
    }
    __syncthreads();
    if (k0 + 32 < K) {
#pragma unroll
      for (int i = 0; i < 4; ++i) pf[i] = *(const f32x4*)(aptr + k0 + 32 + 4 * i);
    }
    // ---- fragments + MFMA ----
    short8 afr[NS][4];
#pragma unroll
    for (int s = 0; s < NS; ++s)
#pragma unroll
      for (int mt = 0; mt < 4; ++mt)
        afr[s][mt] = *(const short8*)&smem[s * 4096 + ra[mt]];
#pragma unroll
    for (int sb = 0; sb < NS; ++sb) {
      short8 bfr[4];
#pragma unroll
      for (int nt = 0; nt < 4; ++nt)
        bfr[nt] = *(const short8*)&smem[NS * 4096 + sb * 4096 + rb[nt]];
#pragma unroll
      for (int sa = 0; sa < NS; ++sa) {
        if (sa + sb <= NS - 1) {
#pragma unroll
          for (int mt = 0; mt < 4; ++mt)
#pragma unroll
            for (int nt = 0; nt < 4; ++nt)
              acc[mt][nt] = __builtin_amdgcn_mfma_f32_16x16x32_bf16(
                  afr[sa][mt], bfr[nt], acc[mt][nt], 0, 0, 0);
        }
      }
    }
  }

  if (MODE < 2) {
    float bv[4];
#pragma unroll
    for (int nt = 0; nt < 4; ++nt) bv[nt] = bias[col0 + wx * 64 + nt * 16 + m15];
#pragma unroll
    for (int mt = 0; mt < 4; ++mt)
#pragma unroll
      for (int reg = 0; reg < 4; ++reg) {
        const int r = row0 + wy * 64 + mt * 16 + q4 * 4 + reg;
#pragma unroll
        for (int nt = 0; nt < 4; ++nt) {
          float v = acc[mt][nt][reg] + bv[nt];
          if (MODE == 0) v = v > 0.f ? v : 0.f;
          Cf[(size_t)r * N + col0 + wx * 64 + nt * 16 + m15] = v;
        }
      }
  } else {
    float invv[4];
#pragma unroll
    for (int nt = 0; nt < 4; ++nt) invv[nt] = invF[col0 + wx * 64 + nt * 16 + m15];
#pragma unroll
    for (int mt = 0; mt < 4; ++mt)
#pragma unroll
      for (int reg = 0; reg < 4; ++reg) {
        float b = acc[mt][0][reg] * invv[0], s = -3.4e38f;
        int bi = col0 + wx * 64 + m15;
#pragma unroll
        for (int nt = 1; nt < 4; ++nt) {
          float v = acc[mt][nt][reg] * invv[nt];
          if (v > b) { s = b; b = v; bi = col0 + wx * 64 + nt * 16 + m15; }
          else       { s = fmaxf(s, v); }
        }
#pragma unroll
        for (int msk = 1; msk < 16; msk <<= 1) {
          float ob = __shfl_xor(b, msk);
          float os = __shfl_xor(s, msk);
          int   oi = __shfl_xor(bi, msk);
          if (ob > b || (ob == b && oi < bi)) { s = fmaxf(b, os); b = ob; bi = oi; }
          else                                 { s = fmaxf(s, ob); }
        }
        if (m15 == 0) {
          const int rl = wy * 64 + mt * 16 + q4 * 4 + reg;
          sb_b[rl][wx] = b; sb_s[rl][wx] = s; sb_i[rl][wx] = bi;
        }
      }
    __syncthreads();
    if (tid < 128) {
      float b = sb_b[tid][0], s = sb_s[tid][0]; int bi = sb_i[tid][0];
      const float b2 = sb_b[tid][1], s2 = sb_s[tid][1]; const int i2 = sb_i[tid][1];
      if (b2 > b) { s = fmaxf(b, s2); b = b2; bi = i2; }
      else        { s = fmaxf(s, b2); }
      const size_t o = (size_t)blockIdx.x * NROWS + row0 + tid;
      pb[o] = b; ps[o] = s; pi[o] = bi;
    }
  }
}

// =====================================================================
// split kernels
// =====================================================================
// W[K][N] fp32 -> 3 transposed planes [N][K] bf16
__global__ __launch_bounds__(256)
void split_t(const float* __restrict__ W, u16* __restrict__ Ph, u16* __restrict__ Pm,
             u16* __restrict__ Pl, int K, int N) {
  __shared__ float t[32][33];
  const int tx = threadIdx.x, ty = threadIdx.y;
  const int n0 = blockIdx.x * 32, k0 = blockIdx.y * 32;
#pragma unroll
  for (int i = 0; i < 4; ++i) t[ty + 8 * i][tx] = W[(size_t)(k0 + ty + 8 * i) * N + n0 + tx];
  __syncthreads();
#pragma unroll
  for (int i = 0; i < 4; ++i) {
    float v = t[tx][ty + 8 * i];
    u16 h, m, l; split3(v, h, m, l);
    const size_t o = (size_t)(n0 + ty + 8 * i) * K + k0 + tx;
    Ph[o] = h; Pm[o] = m; Pl[o] = l;
  }
}

// X (row-major, K-contig) fp32 -> 3 planes bf16 (no transpose)
__global__ __launch_bounds__(256)
void split_nt(const float* __restrict__ X, u16* __restrict__ Ph, u16* __restrict__ Pm,
              u16* __restrict__ Pl, int total4) {
  const int i = blockIdx.x * 256 + threadIdx.x;
  if (i >= total4) return;
  f32x4 v = *(const f32x4*)(X + (size_t)i * 4);
  unsigned long long wh = 0, wm = 0, wl = 0;
#pragma unroll
  for (int j = 0; j < 4; ++j) {
    u16 h, m, l; split3(v[j], h, m, l);
    wh |= (unsigned long long)h << (16 * j);
    wm |= (unsigned long long)m << (16 * j);
    wl |= (unsigned long long)l << (16 * j);
  }
  *(unsigned long long*)(Ph + (size_t)i * 4) = wh;
  *(unsigned long long*)(Pm + (size_t)i * 4) = wm;
  *(unsigned long long*)(Pl + (size_t)i * 4) = wl;
}

// =====================================================================
// merge per-colblock dist partials (16 blocks of 128 codes)
// =====================================================================
__global__ __launch_bounds__(256)
void merge_dist(const float* __restrict__ pb, const float* __restrict__ ps,
                const int* __restrict__ pi, const float* __restrict__ zinv,
                int* __restrict__ codes, int* __restrict__ flags, int mod) {
  const int r = blockIdx.x * 256 + threadIdx.x;
  if (r >= NROWS) return;
  float b = pb[r], s = ps[r]; int bi = pi[r];
  for (int t = 1; t < 16; ++t) {
    float b2 = pb[(size_t)t * NROWS + r], s2 = ps[(size_t)t * NROWS + r];
    if (b2 > b) { s = fmaxf(b, s2); b = b2; bi = pi[(size_t)t * NROWS + r]; }
    else        { s = fmaxf(s, b2); }
  }
  codes[(size_t)r * 3 + mod] = bi;
  if ((b - s) * zinv[r] < TH_SIM) flags[r] |= (1 << mod);
}

// invn: fp64 compute; dual fp64/fp32 output
__global__ __launch_bounds__(256)
void codebook_invnorm(const float* __restrict__ Cb, double* __restrict__ invD,
                      float* __restrict__ invF, int K) {
  const int code = blockIdx.x * 4 + (threadIdx.x >> 6);
  const int lane = threadIdx.x & 63;
  const float* r = Cb + (size_t)code * K;
  double s = 0.0;
  for (int d = lane; d < K; d += 64) { double v = (double)r[d]; s = fma(v, v, s); }
#pragma unroll
  for (int off = 32; off > 0; off >>= 1) s += __shfl_down(s, off, 64);
  if (lane == 0) { double iv = 1.0 / sqrt(s + 1e-12); invD[code] = iv; invF[code] = (float)iv; }
}

__global__ __launch_bounds__(256)
void zinv_rows(const float* __restrict__ Z, float* __restrict__ zinv) {
  const int row = blockIdx.x * 4 + (threadIdx.x >> 6);
  const int lane = threadIdx.x & 63;
  const float* r = Z + (size_t)row * HID;
  float s = 0.f;
  for (int d = lane; d < HID; d += 64) { float v = r[d]; s = fmaf(v, v, s); }
#pragma unroll
  for (int off = 32; off > 0; off >>= 1) s += __shfl_down(s, off, 64);
  if (lane == 0) zinv[row] = rsqrtf(s + 1e-12f);
}

__global__ __launch_bounds__(256)
void row_logits(const float* __restrict__ Hm, const float* __restrict__ ksw,
                double* __restrict__ logits) {
  const int row = blockIdx.x * 4 + (threadIdx.x >> 6);
  const int lane = threadIdx.x & 63;
  const float* r = Hm + (size_t)row * HID;
  double s = 0.0;
  for (int d = lane; d < HID; d += 64) s = fma((double)r[d], (double)ksw[d], s);
#pragma unroll
  for (int off = 32; off > 0; off >>= 1) s += __shfl_down(s, off, 64);
  if (lane == 0) logits[row] = s;
}

template<int N>
__global__ __launch_bounds__(256)
void bitonic_topk(const double* __restrict__ src_val, const int* __restrict__ src_idx,
                  double* __restrict__ dst_val, int* __restrict__ dst_idx,
                  int out_per_block) {
  __shared__ double sv[N];
  __shared__ int    si[N];
  const int tid = threadIdx.x;
  const int base = blockIdx.x * N;
  for (int j = tid; j < N; j += 256) {
    sv[j] = src_val[base + j];
    si[j] = src_idx ? src_idx[base + j] : (base + j);
  }
  __syncthreads();
  for (int k = 2; k <= N; k <<= 1) {
    for (int j2 = k >> 1; j2 > 0; j2 >>= 1) {
      for (int i = tid; i < N; i += 256) {
        const int ixj = i ^ j2;
        if (ixj > i) {
          const double v1 = sv[i], v2 = sv[ixj];
          const int i1 = si[i], i2 = si[ixj];
          const bool bef = (v1 > v2) || (v1 == v2 && i1 < i2);
          const bool up = ((i & k) == 0);
          if (up ? !bef : bef) { sv[i] = v2; sv[ixj] = v1; si[i] = i2; si[ixj] = i1; }
        }
      }
      __syncthreads();
    }
  }
  for (int j = tid; j < out_per_block; j += 256) {
    dst_val[blockIdx.x * out_per_block + j] = sv[j];
    dst_idx[blockIdx.x * out_per_block + j] = si[j];
  }
}

// ---------------- contested-set machinery ----------------
__global__ __launch_bounds__(256)
void zero_init(int* __restrict__ flags, int* __restrict__ rowpos, int* __restrict__ counters) {
  const int r = blockIdx.x * 256 + threadIdx.x;
  if (r < NROWS) { flags[r] = 0; rowpos[r] = 0; }
  if (r < 2) counters[r] = 0;
}

__global__ void cutoff_kernel(const double* __restrict__ c3val, double* __restrict__ cut) {
  if (threadIdx.x == 0) cut[0] = c3val[255] - TH_LOG;
}

__global__ __launch_bounds__(256)
void cand_flag(const double* __restrict__ logits, const double* __restrict__ cut,
               int* __restrict__ flags, int* __restrict__ cand, int* __restrict__ counters) {
  const int r = blockIdx.x * 256 + threadIdx.x;
  if (r >= NROWS) return;
  if (logits[r] >= cut[0]) {
    flags[r] |= 8;
    const int p = atomicAdd(&counters[1], 1);
    if (p < CANDMAX) cand[p] = r;
  }
}

__global__ __launch_bounds__(256)
void build_list(const int* __restrict__ flags, int* __restrict__ list,
                int* __restrict__ rowpos, int* __restrict__ counters, int cap) {
  const int r = blockIdx.x * 256 + threadIdx.x;
  if (r >= NROWS) return;
  if (flags[r]) {
    const int p = atomicAdd(&counters[0], 1);
    if (p < cap) { list[p] = r; rowpos[r] = p; }
  }
}

// =====================================================================
// Exact fp64 recompute on gathered contested rows (validated R1/R2)
// =====================================================================
template<bool RELU, bool GATHER>
__global__ __launch_bounds__(256)
void gemm_rows_f64(const int* __restrict__ list, const int* __restrict__ countp, int cap,
                   const float* __restrict__ Af32, const double* __restrict__ Ad,
                   const float* __restrict__ B, const float* __restrict__ bias,
                   double* __restrict__ Cd, int K) {
  constexpr int BM = 64, BN = 64, BK = 16;
  __shared__ double As[BK][BM + 1];
  __shared__ double Bs[BK][BN + 1];
  int cnt = *countp; cnt = cnt < cap ? cnt : cap;
  const int row0 = blockIdx.y * BM;
  if (row0 >= cnt) return;
  const int col0 = blockIdx.x * BN;
  const int tid = threadIdx.x;
  const int tx = tid & 15, ty = tid >> 4;
  const int ar = tid >> 2, ak = (tid & 3) * 4;
  const int bk = tid >> 4, bc = (tid & 15) * 4;
  const int pa = (row0 + ar < cnt) ? (row0 + ar) : 0;
  const float*  af = nullptr;
  const double* ad = nullptr;
  if (GATHER) af = Af32 + (size_t)list[pa] * K;
  else        ad = Ad + (size_t)pa * HID;
  double acc[4][4] = {};
  for (int k0 = 0; k0 < K; k0 += BK) {
    if (GATHER) {
      const float4 v = *(const float4*)(af + k0 + ak);
      As[ak + 0][ar] = (double)v.x; As[ak + 1][ar] = (double)v.y;
      As[ak + 2][ar] = (double)v.z; As[ak + 3][ar] = (double)v.w;
    } else {
      As[ak + 0][ar] = ad[k0 + ak + 0]; As[ak + 1][ar] = ad[k0 + ak + 1];
      As[ak + 2][ar] = ad[k0 + ak + 2]; As[ak + 3][ar] = ad[k0 + ak + 3];
    }
    const float4 bv = *(const float4*)(B + (size_t)(k0 + bk) * HID + col0 + bc);
    Bs[bk][bc + 0] = (double)bv.x; Bs[bk][bc + 1] = (double)bv.y;
    Bs[bk][bc + 2] = (double)bv.z; Bs[bk][bc + 3] = (double)bv.w;
    __syncthreads();
#pragma unroll
    for (int kk = 0; kk < BK; ++kk) {
      double a0 = As[kk][ty * 4 + 0], a1 = As[kk][ty * 4 + 1];
      double a2 = As[kk][ty * 4 + 2], a3 = As[kk][ty * 4 + 3];
      double b0 = Bs[kk][tx * 4 + 0], b1 = Bs[kk][tx * 4 + 1];
      double b2 = Bs[kk][tx * 4 + 2], b3 = Bs[kk][tx * 4 + 3];
      acc[0][0] = fma(a0, b0, acc[0][0]); acc[0][1] = fma(a0, b1, acc[0][1]);
      acc[0][2] = fma(a0, b2, acc[0][2]); acc[0][3] = fma(a0, b3, acc[0][3]);
      acc[1][0] = fma(a1, b0, acc[1][0]); acc[1][1] = fma(a1, b1, acc[1][1]);
      acc[1][2] = fma(a1, b2, acc[1][2]); acc[1][3] = fma(a1, b3, acc[1][3]);
      acc[2][0] = fma(a2, b0, acc[2][0]); acc[2][1] = fma(a2, b1, acc[2][1]);
      acc[2][2] = fma(a2, b2, acc[2][2]); acc[2][3] = fma(a2, b3, acc[2][3]);
      acc[3][0] = fma(a3, b0, acc[3][0]); acc[3][1] = fma(a3, b1, acc[3][1]);
      acc[3][2] = fma(a3, b2, acc[3][2]); acc[3][3] = fma(a3, b3, acc[3][3]);
    }
    __syncthreads();
  }
#pragma unroll
  for (int i = 0; i < 4; ++i) {
    const int p = row0 + ty * 4 + i;
    if (p >= cnt) continue;
#pragma unroll
    for (int j = 0; j < 4; ++j) {
      double v = acc[i][j] + (double)bias[col0 + tx * 4 + j];
      if (RELU) v = v > 0.0 ? v : 0.0;
      Cd[(size_t)p * HID + col0 + tx * 4 + j] = v;
    }
  }
}

__global__ __launch_bounds__(256)
void dist_exact(const int* __restrict__ countp, int cap,
                const double* __restrict__ zd, const float* __restrict__ Cb,
                const double* __restrict__ invD,
                double* __restrict__ ebest, int* __restrict__ eidx) {
  __shared__ double Zs[16][33];
  __shared__ double Cs[64][33];
  __shared__ double rb[16][17];
  __shared__ int    ri[16][17];
  int cnt = *countp; cnt = cnt < cap ? cnt : cap;
  const int p0 = blockIdx.y * 16;
  if (p0 >= cnt) return;
  const int c0 = blockIdx.x * 64;
  const int tid = threadIdx.x;
  const int row = tid >> 4, cg = (tid & 15) * 4;
  double acc[4] = {};
  const int zr = tid & 15, zk = tid >> 4;
  const int pz = (p0 + zr < cnt) ? (p0 + zr) : p0;
  const int cc = tid & 63, kb = (tid >> 6) * 8;
  for (int k0 = 0; k0 < HID; k0 += 32) {
    const double v0 = zd[(size_t)pz * HID + k0 + zk];
    const double v1 = zd[(size_t)pz * HID + k0 + zk + 16];
    const float4 f0 = *(const float4*)(Cb + (size_t)(c0 + cc) * HID + k0 + kb);
    const float4 f1 = *(const float4*)(Cb + (size_t)(c0 + cc) * HID + k0 + kb + 4);
    if (k0) __syncthreads();
    Zs[zr][zk] = v0; Zs[zr][zk + 16] = v1;
    Cs[cc][kb + 0] = (double)f0.x; Cs[cc][kb + 1] = (double)f0.y;
    Cs[cc][kb + 2] = (double)f0.z; Cs[cc][kb + 3] = (double)f0.w;
    Cs[cc][kb + 4] = (double)f1.x; Cs[cc][kb + 5] = (double)f1.y;
    Cs[cc][kb + 6] = (double)f1.z; Cs[cc][kb + 7] = (double)f1.w;
    __syncthreads();
#pragma unroll 8
    for (int kk = 0; kk < 32; ++kk) {
      const double a = Zs[row][kk];
      acc[0] = fma(a, Cs[cg + 0][kk], acc[0]);
      acc[1] = fma(a, Cs[cg + 1][kk], acc[1]);
      acc[2] = fma(a, Cs[cg + 2][kk], acc[2]);
      acc[3] = fma(a, Cs[cg + 3][kk], acc[3]);
    }
  }
  double best = acc[0] * invD[c0 + cg]; int bi = c0 + cg;
#pragma unroll
  for (int c = 1; c < 4; ++c) {
    const double v = acc[c] * invD[c0 + cg + c];
    if (v > best) { best = v; bi = c0 + cg + c; }
  }
  __syncthreads();
  rb[row][tid & 15] = best; ri[row][tid & 15] = bi;
  __syncthreads();
  if (tid < 16) {
    double b = rb[tid][0]; int i0 = ri[tid][0];
    for (int t = 1; t < 16; ++t) {
      const double v = rb[tid][t];
      if (v > b) { b = v; i0 = ri[tid][t]; }
    }
    if (p0 + tid < cnt) {
      ebest[(size_t)blockIdx.x * cap + p0 + tid] = b;
      eidx [(size_t)blockIdx.x * cap + p0 + tid] = i0;
    }
  }
}

__global__ __launch_bounds__(256)
void dist_exact_merge(const int* __restrict__ countp, int cap, const int* __restrict__ list,
                      const double* __restrict__ ebest, const int* __restrict__ eidx,
                      int* __restrict__ codes, int mod) {
  int cnt = *countp; cnt = cnt < cap ? cnt : cap;
  const int p = blockIdx.x * 256 + threadIdx.x;
  if (p >= cnt) return;
  double b = ebest[p]; int bi = eidx[p];
  for (int t = 1; t < 32; ++t) {
    const double v = ebest[(size_t)t * cap + p];
    if (v > b) { b = v; bi = eidx[(size_t)t * cap + p]; }
  }
  codes[(size_t)list[p] * 3 + mod] = bi;
}

__global__ __launch_bounds__(256)
void logits_exact(const int* __restrict__ candcountp, const int* __restrict__ cand,
                  const int* __restrict__ rowpos, const double* __restrict__ Hd,
                  const float* __restrict__ ksw,
                  double* __restrict__ cvalE, int* __restrict__ cidxE) {
  const int i = blockIdx.x * 4 + (threadIdx.x >> 6);
  const int lane = threadIdx.x & 63;
  int cc = *candcountp; cc = cc < CANDMAX ? cc : CANDMAX;
  if (i >= CANDMAX) return;
  if (i < cc) {
    const int r = cand[i];
    const double* h = Hd + (size_t)rowpos[r] * HID;
    double s = 0.0;
    for (int d = lane; d < HID; d += 64) s = fma(h[d], (double)ksw[d], s);
#pragma unroll
    for (int off = 32; off > 0; off >>= 1) s += __shfl_down(s, off, 64);
    if (lane == 0) { cvalE[i] = s; cidxE[i] = r; }
  } else if (lane == 0) {
    cvalE[i] = -1e300; cidxE[i] = 0x7FFFFFFF;
  }
}

__global__ void finalize2(const int* __restrict__ kidx, int* __restrict__ out) {
  const int t = threadIdx.x;
  const int k = kidx[t];
  out[NROWS * 3 + t] = k;
  int* sel = out + NROWS * 3 + TOPM;
  sel[t * 3 + 0] = out[(size_t)k * 3 + 0];
  sel[t * 3 + 1] = out[(size_t)k * 3 + 1];
  sel[t * 3 + 2] = out[(size_t)k * 3 + 2];
}

// =====================================================================
extern "C" void kernel_launch(void* const* d_in, const int* in_sizes, int n_in,
                              void* d_out, int out_size, void* d_ws, size_t ws_size,
                              hipStream_t stream) {
  const float* h0  = (const float*)d_in[0];
  const float* W1  = (const float*)d_in[1];
  const float* b1  = (const float*)d_in[2];
  const float* W2  = (const float*)d_in[3];
  const float* b2  = (const float*)d_in[4];
  const float* Wm  = (const float*)d_in[5];
  const float* bm  = (const float*)d_in[6];
  const float* Wt  = (const float*)d_in[7];
  const float* bt  = (const float*)d_in[8];
  const float* Wp  = (const float*)d_in[9];
  const float* bp  = (const float*)d_in[10];
  const float* Cm  = (const float*)d_in[11];
  const float* Ct  = (const float*)d_in[12];
  const float* Cp  = (const float*)d_in[13];
  const float* ksw = (const float*)d_in[14];
  int* out = (int*)d_out;

  size_t fixed = (size_t)NROWS * HID * 4 * 2               // Hf, Zf
               + (size_t)3 * HID * DIN * 2                  // W1t planes
               + (size_t)4 * 3 * HID * HID * 2              // W2t/Wmt/Wtt/Wpt
               + (size_t)3 * 3 * CS * HID * 2               // Cb planes
               + (size_t)16 * NROWS * 12                    // pb ps pi
               + (size_t)NROWS * 24
               + (size_t)3 * CS * 12 + (8 << 20);
  long long rem = (long long)ws_size - (long long)fixed;
  int cap = (int)(rem / 16800);
  cap = cap < 1024 ? 1024 : (cap > 6144 ? 6144 : cap);
  cap &= ~63;

  char* ws = (char*)d_ws;
  size_t off = 0;
  auto alloc = [&](size_t bytes) { void* p = ws + off; off = (off + bytes + 255) & ~(size_t)255; return p; };
  double* Hd     = (double*)alloc((size_t)cap * HID * 8);
  double* H1d    = (double*)alloc((size_t)cap * HID * 8);   // reused as zd
  double* ebest  = (double*)alloc((size_t)32 * cap * 8);
  double* logits = (double*)alloc((size_t)NROWS * 8);
  double* cvalA  = (double*)alloc(8192 * 8);
  double* c2val  = (double*)alloc(2048 * 8);
  double* c3val  = (double*)alloc(256 * 8);
  double* cvalE  = (double*)alloc(CANDMAX * 8);
  double* kval   = (double*)alloc(256 * 8);
  double* invD   = (double*)alloc((size_t)3 * CS * 8);
  double* cut    = (double*)alloc(256);
  float* Hf      = (float*)alloc((size_t)NROWS * HID * 4);
  float* Zf      = (float*)alloc((size_t)NROWS * HID * 4);  // H1, then z
  float* pb      = (float*)alloc((size_t)16 * NROWS * 4);
  float* ps      = (float*)alloc((size_t)16 * NROWS * 4);
  float* invF    = (float*)alloc((size_t)3 * CS * 4);
  float* zinv    = (float*)alloc((size_t)NROWS * 4);
  u16* w1t       = (u16*)alloc((size_t)3 * HID * DIN * 2);
  u16* w2t       = (u16*)alloc((size_t)3 * HID * HID * 2);
  u16* wmt       = (u16*)alloc((size_t)3 * HID * HID * 2);
  u16* wtt       = (u16*)alloc((size_t)3 * HID * HID * 2);
  u16* wpt       = (u16*)alloc((size_t)3 * HID * HID * 2);
  u16* cbp       = (u16*)alloc((size_t)3 * 3 * CS * HID * 2);
  int* pi        = (int*)alloc((size_t)16 * NROWS * 4);
  int* eidx      = (int*)alloc((size_t)32 * cap * 4);
  int* cidxA     = (int*)alloc(8192 * 4);
  int* c2idx     = (int*)alloc(2048 * 4);
  int* c3idx     = (int*)alloc(256 * 4);
  int* cidxE     = (int*)alloc(CANDMAX * 4);
  int* kidx      = (int*)alloc(256 * 4);
  int* flags     = (int*)alloc((size_t)NROWS * 4);
  int* rowpos    = (int*)alloc((size_t)NROWS * 4);
  int* list      = (int*)alloc((size_t)cap * 4);
  int* cand      = (int*)alloc(CANDMAX * 4);
  int* counters  = (int*)alloc(64);

  const dim3 blk(256);
  const float* Wmods[3] = {Wm, Wt, Wp};
  const float* bmods[3] = {bm, bt, bp};
  const float* Cmods[3] = {Cm, Ct, Cp};
  u16* wmodt[3] = {wmt, wtt, wpt};

  zero_init<<<dim3(NROWS / 256), blk, 0, stream>>>(flags, rowpos, counters);

  // ---- split weights (transposed) and codebooks ----
  const size_t p1 = (size_t)HID * DIN, pH = (size_t)HID * HID, pC = (size_t)CS * HID;
  split_t<<<dim3(HID / 32, DIN / 32), dim3(32, 8), 0, stream>>>(W1, w1t, w1t + p1, w1t + 2 * p1, DIN, HID);
  split_t<<<dim3(HID / 32, HID / 32), dim3(32, 8), 0, stream>>>(W2, w2t, w2t + pH, w2t + 2 * pH, HID, HID);
  for (int mod = 0; mod < 3; ++mod) {
    split_t<<<dim3(HID / 32, HID / 32), dim3(32, 8), 0, stream>>>(
        Wmods[mod], wmodt[mod], wmodt[mod] + pH, wmodt[mod] + 2 * pH, HID, HID);
    u16* cb = cbp + (size_t)mod * 3 * pC;
    split_nt<<<dim3((int)(pC / 4 / 256)), blk, 0, stream>>>(Cmods[mod], cb, cb + pC, cb + 2 * pC, (int)(pC / 4));
    codebook_invnorm<<<dim3(CS / 4), blk, 0, stream>>>(Cmods[mod], invD + mod * CS, invF + mod * CS, HID);
  }

  // ---- MFMA phase A ----
  gemm3<0, 3><<<dim3(HID / 128, NROWS / 128), blk, 0, stream>>>(
      h0, w1t, w1t + p1, w1t + 2 * p1, b1, Zf, nullptr, nullptr, nullptr, nullptr, HID, DIN);
  gemm3<0, 3><<<dim3(HID / 128, NROWS / 128), blk, 0, stream>>>(
      Zf, w2t, w2t + pH, w2t + 2 * pH, b2, Hf, nullptr, nullptr, nullptr, nullptr, HID, HID);
  row_logits<<<dim3(NROWS / 4), blk, 0, stream>>>(Hf, ksw, logits);

  for (int mod = 0; mod < 3; ++mod) {
    gemm3<1, 3><<<dim3(HID / 128, NROWS / 128), blk, 0, stream>>>(
        Hf, wmodt[mod], wmodt[mod] + pH, wmodt[mod] + 2 * pH, bmods[mod], Zf,
        nullptr, nullptr, nullptr, nullptr, HID, HID);
    zinv_rows<<<dim3(NROWS / 4), blk, 0, stream>>>(Zf, zinv);
    u16* cb = cbp + (size_t)mod * 3 * pC;
    gemm3<2, 2><<<dim3(CS / 128, NROWS / 128), blk, 0, stream>>>(
        Zf, cb, cb + pC, nullptr, nullptr, nullptr, invF + mod * CS, pb, ps, pi, CS, HID);
    merge_dist<<<dim3(NROWS / 256), blk, 0, stream>>>(pb, ps, pi, zinv, out, flags, mod);
  }

  // ---- approx top-k banding ----
  bitonic_topk<1024><<<dim3(32), blk, 0, stream>>>(logits, nullptr, cvalA, cidxA, 256);
  bitonic_topk<1024><<<dim3(8), blk, 0, stream>>>(cvalA, cidxA, c2val, c2idx, 256);
  bitonic_topk<2048><<<dim3(1), blk, 0, stream>>>(c2val, c2idx, c3val, c3idx, 256);
  cutoff_kernel<<<dim3(1), dim3(64), 0, stream>>>(c3val, cut);
  cand_flag<<<dim3(NROWS / 256), blk, 0, stream>>>(logits, cut, flags, cand, counters);
  build_list<<<dim3(NROWS / 256), blk, 0, stream>>>(flags, list, rowpos, counters, cap);

  // ---- exact fp64 refine of contested rows ----
  gemm_rows_f64<true, true><<<dim3(HID / 64, cap / 64), blk, 0, stream>>>(
      list, counters, cap, h0, nullptr, W1, b1, H1d, DIN);
  gemm_rows_f64<true, false><<<dim3(HID / 64, cap / 64), blk, 0, stream>>>(
      list, counters, cap, nullptr, H1d, W2, b2, Hd, HID);
  for (int mod = 0; mod < 3; ++mod) {
    gemm_rows_f64<false, false><<<dim3(HID / 64, cap / 64), blk, 0, stream>>>(
        list, counters, cap, nullptr, Hd, Wmods[mod], bmods[mod], H1d, HID);
    dist_exact<<<dim3(CS / 64, cap / 16), blk, 0, stream>>>(
        counters, cap, H1d, Cmods[mod], invD + mod * CS, ebest, eidx);
    dist_exact_merge<<<dim3((cap + 255) / 256), blk, 0, stream>>>(
        counters, cap, list, ebest, eidx, out, mod);
  }

  // ---- exact top-256 ----
  logits_exact<<<dim3(CANDMAX / 4), blk, 0, stream>>>(counters + 1, cand, rowpos, Hd, ksw, cvalE, cidxE);
  bitonic_topk<2048><<<dim3(1), blk, 0, stream>>>(cvalE, cidxE, kval, kidx, 256);
  finalize2<<<dim3(1), blk, 0, stream>>>(kidx, out);
}

// Round 4
// 6454.345 us; speedup vs baseline: 3.3673x; 1.7188x over previous
//
#include <hip/hip_runtime.h>
#include <cstdint>
#include <cstddef>

typedef unsigned short u16;
typedef unsigned int u32;
typedef __attribute__((ext_vector_type(8))) short short8;
typedef __attribute__((ext_vector_type(4))) float f32x4;

constexpr int NROWS = 32768;
constexpr int DIN   = 2048;
constexpr int HID   = 1024;
constexpr int CS    = 2048;
constexpr int TOPM  = 256;
constexpr float  TH_SIM = 2e-4f;   // cosine-margin threshold for contested rows
constexpr double TH_LOG = 1e-3;    // logit band for top-k candidates
constexpr int CANDMAX = 2048;

// ---------------------------------------------------------------------
// bf16 split helpers
// ---------------------------------------------------------------------
__device__ __forceinline__ u16 f2bf(float x) {
  u32 u = __float_as_uint(x);
  u += 0x7FFF + ((u >> 16) & 1);          // RNE
  return (u16)(u >> 16);
}
__device__ __forceinline__ float bf2f(u16 h) { return __uint_as_float(((u32)h) << 16); }
__device__ __forceinline__ void split3(float x, u16& h, u16& m, u16& l) {
  h = f2bf(x); float r = x - bf2f(h);
  m = f2bf(r); float r2 = r - bf2f(m);
  l = f2bf(r2);
}

__device__ __forceinline__ void async16(const u16* gp, const u16* lp) {
  __builtin_amdgcn_global_load_lds(
      (const __attribute__((address_space(1))) unsigned int*)gp,
      (__attribute__((address_space(3))) unsigned int*)(unsigned int)(uintptr_t)lp,
      16, 0, 0);
}

// =====================================================================
// gemm3: C = A(fp32, split-in-staging, bf16xNS) @ B(pre-split planes)^T
// 128x128 tile, BK=32, 4 waves (2x2), wave tile 64x64, 4x4 MFMA 16x16x32.
// MODE 0: relu(acc+bias)->Cf ; MODE 1: acc+bias->Cf ; MODE 2: dist argmax
// =====================================================================
template<int MODE, int NS>
__global__ __launch_bounds__(256)
void gemm3(const float* __restrict__ Af,
           const u16* __restrict__ B0, const u16* __restrict__ B1, const u16* __restrict__ B2,
           const float* __restrict__ bias, float* __restrict__ Cf,
           const float* __restrict__ invF,
           float* __restrict__ pb, float* __restrict__ ps, int* __restrict__ pi,
           int N, int K) {
  __shared__ u16 smem[NS * 2 * 4096];   // A: NS x 8KB, B: NS x 8KB
  __shared__ float sb_b[128][2];
  __shared__ float sb_s[128][2];
  __shared__ int   sb_i[128][2];

  const int tid = threadIdx.x, lane = tid & 63, wv = tid >> 6;
  const int wy = wv >> 1, wx = wv & 1;
  const int m15 = lane & 15, q4 = lane >> 4;
  const int row0 = blockIdx.y * 128, col0 = blockIdx.x * 128;
  const u16* Bp[3] = {B0, B1, B2};

  f32x4 acc[4][4] = {};

  const int r_ = tid >> 1, hf = tid & 1;
  const float* aptr = Af + (size_t)(row0 + r_) * K + hf * 16;
  const int swA = (r_ >> 1) & 3;

  const int brloc = lane >> 2;
  const int bq = (lane & 3) ^ ((lane >> 3) & 3);

  int ra[4], rb[4];
#pragma unroll
  for (int mt = 0; mt < 4; ++mt) {
    int r = wy * 64 + mt * 16 + m15;
    ra[mt] = r * 32 + ((q4 ^ ((r >> 1) & 3)) * 8);
  }
#pragma unroll
  for (int nt = 0; nt < 4; ++nt) {
    int n = wx * 64 + nt * 16 + m15;
    rb[nt] = n * 32 + ((q4 ^ ((n >> 1) & 3)) * 8);
  }

  f32x4 pf[4];
#pragma unroll
  for (int i = 0; i < 4; ++i) pf[i] = *(const f32x4*)(aptr + 4 * i);

  for (int k0 = 0; k0 < K; k0 += 32) {
    if (k0) __syncthreads();
#pragma unroll
    for (int c = 0; c < 2; ++c) {
      const int q = 2 * hf + c;
      const int slot = q ^ swA;
      float f[8];
#pragma unroll
      for (int j = 0; j < 4; ++j) { f[j] = pf[2 * c][j]; f[4 + j] = pf[2 * c + 1][j]; }
      u16 hh[8], mm[8], ll[8];
#pragma unroll
      for (int j = 0; j < 8; ++j) split3(f[j], hh[j], mm[j], ll[j]);
      const int base = r_ * 32 + slot * 8;
      short8 v0, v1, v2;
#pragma unroll
      for (int j = 0; j < 8; ++j) { v0[j] = (short)hh[j]; v1[j] = (short)mm[j]; v2[j] = (short)ll[j]; }
      *(short8*)&smem[base] = v0;
      if (NS > 1) *(short8*)&smem[4096 + base] = v1;
      if (NS > 2) *(short8*)&smem[8192 + base] = v2;
    }
#pragma unroll
    for (int i = 0; i < NS * 2; ++i) {
      const int idx = wv * (NS * 2) + i;
      const int s = idx >> 3, j = idx & 7;
      const u16* gp = Bp[s] + (size_t)(col0 + 16 * j + brloc) * K + k0 + bq * 8;
      async16(gp, &smem[NS * 4096 + s * 4096 + j * 512]);
    }
    __syncthreads();
    if (k0 + 32 < K) {
#pragma unroll
      for (int i = 0; i < 4; ++i) pf[i] = *(const f32x4*)(aptr + k0 + 32 + 4 * i);
    }
    short8 afr[NS][4];
#pragma unroll
    for (int s = 0; s < NS; ++s)
#pragma unroll
      for (int mt = 0; mt < 4; ++mt)
        afr[s][mt] = *(const short8*)&smem[s * 4096 + ra[mt]];
#pragma unroll
    for (int sb = 0; sb < NS; ++sb) {
      short8 bfr[4];
#pragma unroll
      for (int nt = 0; nt < 4; ++nt)
        bfr[nt] = *(const short8*)&smem[NS * 4096 + sb * 4096 + rb[nt]];
#pragma unroll
      for (int sa = 0; sa < NS; ++sa) {
        if (sa + sb <= NS - 1) {
#pragma unroll
          for (int mt = 0; mt < 4; ++mt)
#pragma unroll
            for (int nt = 0; nt < 4; ++nt)
              acc[mt][nt] = __builtin_amdgcn_mfma_f32_16x16x32_bf16(
                  afr[sa][mt], bfr[nt], acc[mt][nt], 0, 0, 0);
        }
      }
    }
  }

  if (MODE < 2) {
    float bv[4];
#pragma unroll
    for (int nt = 0; nt < 4; ++nt) bv[nt] = bias[col0 + wx * 64 + nt * 16 + m15];
#pragma unroll
    for (int mt = 0; mt < 4; ++mt)
#pragma unroll
      for (int reg = 0; reg < 4; ++reg) {
        const int r = row0 + wy * 64 + mt * 16 + q4 * 4 + reg;
#pragma unroll
        for (int nt = 0; nt < 4; ++nt) {
          float v = acc[mt][nt][reg] + bv[nt];
          if (MODE == 0) v = v > 0.f ? v : 0.f;
          Cf[(size_t)r * N + col0 + wx * 64 + nt * 16 + m15] = v;
        }
      }
  } else {
    float invv[4];
#pragma unroll
    for (int nt = 0; nt < 4; ++nt) invv[nt] = invF[col0 + wx * 64 + nt * 16 + m15];
#pragma unroll
    for (int mt = 0; mt < 4; ++mt)
#pragma unroll
      for (int reg = 0; reg < 4; ++reg) {
        float b = acc[mt][0][reg] * invv[0], s = -3.4e38f;
        int bi = col0 + wx * 64 + m15;
#pragma unroll
        for (int nt = 1; nt < 4; ++nt) {
          float v = acc[mt][nt][reg] * invv[nt];
          if (v > b) { s = b; b = v; bi = col0 + wx * 64 + nt * 16 + m15; }
          else       { s = fmaxf(s, v); }
        }
#pragma unroll
        for (int msk = 1; msk < 16; msk <<= 1) {
          float ob = __shfl_xor(b, msk);
          float os = __shfl_xor(s, msk);
          int   oi = __shfl_xor(bi, msk);
          if (ob > b || (ob == b && oi < bi)) { s = fmaxf(b, os); b = ob; bi = oi; }
          else                                 { s = fmaxf(s, ob); }
        }
        if (m15 == 0) {
          const int rl = wy * 64 + mt * 16 + q4 * 4 + reg;
          sb_b[rl][wx] = b; sb_s[rl][wx] = s; sb_i[rl][wx] = bi;
        }
      }
    __syncthreads();
    if (tid < 128) {
      float b = sb_b[tid][0], s = sb_s[tid][0]; int bi = sb_i[tid][0];
      const float b2 = sb_b[tid][1], s2 = sb_s[tid][1]; const int i2 = sb_i[tid][1];
      if (b2 > b) { s = fmaxf(b, s2); b = b2; bi = i2; }
      else        { s = fmaxf(s, b2); }
      const size_t o = (size_t)blockIdx.x * NROWS + row0 + tid;
      pb[o] = b; ps[o] = s; pi[o] = bi;
    }
  }
}

// =====================================================================
// split kernels
// =====================================================================
__global__ __launch_bounds__(256)
void split_t(const float* __restrict__ W, u16* __restrict__ Ph, u16* __restrict__ Pm,
             u16* __restrict__ Pl, int K, int N) {
  __shared__ float t[32][33];
  const int tx = threadIdx.x, ty = threadIdx.y;
  const int n0 = blockIdx.x * 32, k0 = blockIdx.y * 32;
#pragma unroll
  for (int i = 0; i < 4; ++i) t[ty + 8 * i][tx] = W[(size_t)(k0 + ty + 8 * i) * N + n0 + tx];
  __syncthreads();
#pragma unroll
  for (int i = 0; i < 4; ++i) {
    float v = t[tx][ty + 8 * i];
    u16 h, m, l; split3(v, h, m, l);
    const size_t o = (size_t)(n0 + ty + 8 * i) * K + k0 + tx;
    Ph[o] = h; Pm[o] = m; Pl[o] = l;
  }
}

__global__ __launch_bounds__(256)
void split_nt(const float* __restrict__ X, u16* __restrict__ Ph, u16* __restrict__ Pm,
              u16* __restrict__ Pl, int total4) {
  const int i = blockIdx.x * 256 + threadIdx.x;
  if (i >= total4) return;
  f32x4 v = *(const f32x4*)(X + (size_t)i * 4);
  unsigned long long wh = 0, wm = 0, wl = 0;
#pragma unroll
  for (int j = 0; j < 4; ++j) {
    u16 h, m, l; split3(v[j], h, m, l);
    wh |= (unsigned long long)h << (16 * j);
    wm |= (unsigned long long)m << (16 * j);
    wl |= (unsigned long long)l << (16 * j);
  }
  *(unsigned long long*)(Ph + (size_t)i * 4) = wh;
  *(unsigned long long*)(Pm + (size_t)i * 4) = wm;
  *(unsigned long long*)(Pl + (size_t)i * 4) = wl;
}

// =====================================================================
__global__ __launch_bounds__(256)
void merge_dist(const float* __restrict__ pb, const float* __restrict__ ps,
                const int* __restrict__ pi, const float* __restrict__ zinv,
                int* __restrict__ codes, int* __restrict__ flags, int mod) {
  const int r = blockIdx.x * 256 + threadIdx.x;
  if (r >= NROWS) return;
  float b = pb[r], s = ps[r]; int bi = pi[r];
  for (int t = 1; t < 16; ++t) {
    float b2 = pb[(size_t)t * NROWS + r], s2 = ps[(size_t)t * NROWS + r];
    if (b2 > b) { s = fmaxf(b, s2); b = b2; bi = pi[(size_t)t * NROWS + r]; }
    else        { s = fmaxf(s, b2); }
  }
  codes[(size_t)r * 3 + mod] = bi;
  if ((b - s) * zinv[r] < TH_SIM) flags[r] |= (1 << mod);
}

__global__ __launch_bounds__(256)
void codebook_invnorm(const float* __restrict__ Cb, double* __restrict__ invD,
                      float* __restrict__ invF, int K) {
  const int code = blockIdx.x * 4 + (threadIdx.x >> 6);
  const int lane = threadIdx.x & 63;
  const float* r = Cb + (size_t)code * K;
  double s = 0.0;
  for (int d = lane; d < K; d += 64) { double v = (double)r[d]; s = fma(v, v, s); }
#pragma unroll
  for (int off = 32; off > 0; off >>= 1) s += __shfl_down(s, off, 64);
  if (lane == 0) { double iv = 1.0 / sqrt(s + 1e-12); invD[code] = iv; invF[code] = (float)iv; }
}

__global__ __launch_bounds__(256)
void zinv_rows(const float* __restrict__ Z, float* __restrict__ zinv) {
  const int row = blockIdx.x * 4 + (threadIdx.x >> 6);
  const int lane = threadIdx.x & 63;
  const float* r = Z + (size_t)row * HID;
  float s = 0.f;
  for (int d = lane; d < HID; d += 64) { float v = r[d]; s = fmaf(v, v, s); }
#pragma unroll
  for (int off = 32; off > 0; off >>= 1) s += __shfl_down(s, off, 64);
  if (lane == 0) zinv[row] = rsqrtf(s + 1e-12f);
}

__global__ __launch_bounds__(256)
void row_logits(const float* __restrict__ Hm, const float* __restrict__ ksw,
                double* __restrict__ logits) {
  const int row = blockIdx.x * 4 + (threadIdx.x >> 6);
  const int lane = threadIdx.x & 63;
  const float* r = Hm + (size_t)row * HID;
  double s = 0.0;
  for (int d = lane; d < HID; d += 64) s = fma((double)r[d], (double)ksw[d], s);
#pragma unroll
  for (int off = 32; off > 0; off >>= 1) s += __shfl_down(s, off, 64);
  if (lane == 0) logits[row] = s;
}

template<int N>
__global__ __launch_bounds__(256)
void bitonic_topk(const double* __restrict__ src_val, const int* __restrict__ src_idx,
                  double* __restrict__ dst_val, int* __restrict__ dst_idx,
                  int out_per_block) {
  __shared__ double sv[N];
  __shared__ int    si[N];
  const int tid = threadIdx.x;
  const int base = blockIdx.x * N;
  for (int j = tid; j < N; j += 256) {
    sv[j] = src_val[base + j];
    si[j] = src_idx ? src_idx[base + j] : (base + j);
  }
  __syncthreads();
  for (int k = 2; k <= N; k <<= 1) {
    for (int j2 = k >> 1; j2 > 0; j2 >>= 1) {
      for (int i = tid; i < N; i += 256) {
        const int ixj = i ^ j2;
        if (ixj > i) {
          const double v1 = sv[i], v2 = sv[ixj];
          const int i1 = si[i], i2 = si[ixj];
          const bool bef = (v1 > v2) || (v1 == v2 && i1 < i2);
          const bool up = ((i & k) == 0);
          if (up ? !bef : bef) { sv[i] = v2; sv[ixj] = v1; si[i] = i2; si[ixj] = i1; }
        }
      }
      __syncthreads();
    }
  }
  for (int j = tid; j < out_per_block; j += 256) {
    dst_val[blockIdx.x * out_per_block + j] = sv[j];
    dst_idx[blockIdx.x * out_per_block + j] = si[j];
  }
}

// ---------------- contested-set machinery ----------------
__global__ __launch_bounds__(256)
void zero_init(int* __restrict__ flags, int* __restrict__ rowpos, int* __restrict__ counters) {
  const int r = blockIdx.x * 256 + threadIdx.x;
  if (r < NROWS) { flags[r] = 0; rowpos[r] = 0; }
  if (r < 8) counters[r] = 0;
}

__global__ void cutoff_kernel(const double* __restrict__ c3val, double* __restrict__ cut) {
  if (threadIdx.x == 0) cut[0] = c3val[255] - TH_LOG;
}

__global__ __launch_bounds__(256)
void cand_flag(const double* __restrict__ logits, const double* __restrict__ cut,
               int* __restrict__ flags, int* __restrict__ cand, int* __restrict__ counters) {
  const int r = blockIdx.x * 256 + threadIdx.x;
  if (r >= NROWS) return;
  if (logits[r] >= cut[0]) {
    flags[r] |= 8;
    const int p = atomicAdd(&counters[1], 1);
    if (p < CANDMAX) cand[p] = r;
  }
}

// union list (encoder refine + rowpos) and per-mod lists
__global__ __launch_bounds__(256)
void build_lists(const int* __restrict__ flags, int* __restrict__ ulist,
                 int* __restrict__ rowpos, int* __restrict__ lm0, int* __restrict__ lm1,
                 int* __restrict__ lm2, int* __restrict__ counters, int cap) {
  const int r = blockIdx.x * 256 + threadIdx.x;
  if (r >= NROWS) return;
  const int f = flags[r];
  if (!f) return;
  const int p = atomicAdd(&counters[0], 1);
  if (p < cap) { ulist[p] = r; rowpos[r] = p; }
  if (f & 1) { const int q = atomicAdd(&counters[2], 1); if (q < cap) lm0[q] = r; }
  if (f & 2) { const int q = atomicAdd(&counters[3], 1); if (q < cap) lm1[q] = r; }
  if (f & 4) { const int q = atomicAdd(&counters[4], 1); if (q < cap) lm2[q] = r; }
}

// =====================================================================
// Exact fp64 GEMM on gathered rows. GM: 0 = gather fp32 by list,
// 1 = dense double by position, 2 = gather double via rowpos[list[p]].
// =====================================================================
template<bool RELU, int GM>
__global__ __launch_bounds__(256)
void gemm_rows_f64(const int* __restrict__ list, const int* __restrict__ rowpos,
                   const int* __restrict__ countp, int cap,
                   const float* __restrict__ Af32, const double* __restrict__ Ad,
                   const float* __restrict__ B, const float* __restrict__ bias,
                   double* __restrict__ Cd, int K) {
  constexpr int BM = 64, BN = 64, BK = 16;
  __shared__ double As[BK][BM + 1];
  __shared__ double Bs[BK][BN + 1];
  int cnt = *countp; cnt = cnt < cap ? cnt : cap;
  const int row0 = blockIdx.y * BM;
  if (row0 >= cnt) return;
  const int col0 = blockIdx.x * BN;
  const int tid = threadIdx.x;
  const int tx = tid & 15, ty = tid >> 4;
  const int ar = tid >> 2, ak = (tid & 3) * 4;
  const int bk = tid >> 4, bc = (tid & 15) * 4;
  const int pa = (row0 + ar < cnt) ? (row0 + ar) : 0;
  const float*  af = nullptr;
  const double* ad = nullptr;
  if (GM == 0)      af = Af32 + (size_t)list[pa] * K;
  else if (GM == 1) ad = Ad + (size_t)pa * HID;
  else              ad = Ad + (size_t)rowpos[list[pa]] * HID;
  double acc[4][4] = {};
  for (int k0 = 0; k0 < K; k0 += BK) {
    if (GM == 0) {
      const float4 v = *(const float4*)(af + k0 + ak);
      As[ak + 0][ar] = (double)v.x; As[ak + 1][ar] = (double)v.y;
      As[ak + 2][ar] = (double)v.z; As[ak + 3][ar] = (double)v.w;
    } else {
      As[ak + 0][ar] = ad[k0 + ak + 0]; As[ak + 1][ar] = ad[k0 + ak + 1];
      As[ak + 2][ar] = ad[k0 + ak + 2]; As[ak + 3][ar] = ad[k0 + ak + 3];
    }
    const float4 bv = *(const float4*)(B + (size_t)(k0 + bk) * HID + col0 + bc);
    Bs[bk][bc + 0] = (double)bv.x; Bs[bk][bc + 1] = (double)bv.y;
    Bs[bk][bc + 2] = (double)bv.z; Bs[bk][bc + 3] = (double)bv.w;
    __syncthreads();
#pragma unroll
    for (int kk = 0; kk < BK; ++kk) {
      double a0 = As[kk][ty * 4 + 0], a1 = As[kk][ty * 4 + 1];
      double a2 = As[kk][ty * 4 + 2], a3 = As[kk][ty * 4 + 3];
      double b0 = Bs[kk][tx * 4 + 0], b1 = Bs[kk][tx * 4 + 1];
      double b2 = Bs[kk][tx * 4 + 2], b3 = Bs[kk][tx * 4 + 3];
      acc[0][0] = fma(a0, b0, acc[0][0]); acc[0][1] = fma(a0, b1, acc[0][1]);
      acc[0][2] = fma(a0, b2, acc[0][2]); acc[0][3] = fma(a0, b3, acc[0][3]);
      acc[1][0] = fma(a1, b0, acc[1][0]); acc[1][1] = fma(a1, b1, acc[1][1]);
      acc[1][2] = fma(a1, b2, acc[1][2]); acc[1][3] = fma(a1, b3, acc[1][3]);
      acc[2][0] = fma(a2, b0, acc[2][0]); acc[2][1] = fma(a2, b1, acc[2][1]);
      acc[2][2] = fma(a2, b2, acc[2][2]); acc[2][3] = fma(a2, b3, acc[2][3]);
      acc[3][0] = fma(a3, b0, acc[3][0]); acc[3][1] = fma(a3, b1, acc[3][1]);
      acc[3][2] = fma(a3, b2, acc[3][2]); acc[3][3] = fma(a3, b3, acc[3][3]);
    }
    __syncthreads();
  }
#pragma unroll
  for (int i = 0; i < 4; ++i) {
    const int p = row0 + ty * 4 + i;
    if (p >= cnt) continue;
#pragma unroll
    for (int j = 0; j < 4; ++j) {
      double v = acc[i][j] + (double)bias[col0 + tx * 4 + j];
      if (RELU) v = v > 0.0 ? v : 0.0;
      Cd[(size_t)p * HID + col0 + tx * 4 + j] = v;
    }
  }
}

// =====================================================================
// dist_exact2: 32 rows x 128 codes per block, KC=32, fp64.
// Transposed LDS layouts, b128-aligned, bank-wrap-floor access.
// Thread (rg=t>>5, cgi=t&31): rows rg*4..+3, codes cgi*4..+3.
// =====================================================================
__global__ __launch_bounds__(256)
void dist_exact2(const int* __restrict__ countp, int cap,
                 const double* __restrict__ zd, const float* __restrict__ Cb,
                 const double* __restrict__ invD,
                 double* __restrict__ ebest, int* __restrict__ eidx) {
  __shared__ double Zs[32][38];    // [kk][row], stride 38: 16B-aligned rows, 4-way-floor writes
  __shared__ double Cs[32][132];   // [kk][code], stride 132: 16B-aligned
  int cnt = *countp; cnt = cnt < cap ? cnt : cap;
  const int p0 = blockIdx.y * 32;
  if (p0 >= cnt) return;
  const int c0 = blockIdx.x * 128;
  const int tid = threadIdx.x;
  const int rg = tid >> 5, cgi = tid & 31;
  // staging roles
  const int zr = tid >> 3, zk = (tid & 7) * 4;       // Z: 32 rows x 32 k
  const int sc = tid & 31, skb = (tid >> 5) * 4;     // C: codes sc+32g, k skb..skb+3
  const int pz = (p0 + zr < cnt) ? (p0 + zr) : 0;
  const double* zrow = zd + (size_t)pz * HID;
  double acc[4][4] = {};

  for (int k0 = 0; k0 < HID; k0 += 32) {
    if (k0) __syncthreads();
    double2 za = *(const double2*)(zrow + k0 + zk);
    double2 zb = *(const double2*)(zrow + k0 + zk + 2);
    Zs[zk + 0][zr] = za.x; Zs[zk + 1][zr] = za.y;
    Zs[zk + 2][zr] = zb.x; Zs[zk + 3][zr] = zb.y;
#pragma unroll
    for (int g = 0; g < 4; ++g) {
      const int code = sc + 32 * g;
      const float4 f = *(const float4*)(Cb + (size_t)(c0 + code) * HID + k0 + skb);
      Cs[skb + 0][code] = (double)f.x; Cs[skb + 1][code] = (double)f.y;
      Cs[skb + 2][code] = (double)f.z; Cs[skb + 3][code] = (double)f.w;
    }
    __syncthreads();
#pragma unroll
    for (int kk = 0; kk < 32; ++kk) {
      const double2 z01 = *(const double2*)&Zs[kk][rg * 4];
      const double2 z23 = *(const double2*)&Zs[kk][rg * 4 + 2];
      const double2 c01 = *(const double2*)&Cs[kk][cgi * 4];
      const double2 c23 = *(const double2*)&Cs[kk][cgi * 4 + 2];
      acc[0][0] = fma(z01.x, c01.x, acc[0][0]); acc[0][1] = fma(z01.x, c01.y, acc[0][1]);
      acc[0][2] = fma(z01.x, c23.x, acc[0][2]); acc[0][3] = fma(z01.x, c23.y, acc[0][3]);
      acc[1][0] = fma(z01.y, c01.x, acc[1][0]); acc[1][1] = fma(z01.y, c01.y, acc[1][1]);
      acc[1][2] = fma(z01.y, c23.x, acc[1][2]); acc[1][3] = fma(z01.y, c23.y, acc[1][3]);
      acc[2][0] = fma(z23.x, c01.x, acc[2][0]); acc[2][1] = fma(z23.x, c01.y, acc[2][1]);
      acc[2][2] = fma(z23.x, c23.x, acc[2][2]); acc[2][3] = fma(z23.x, c23.y, acc[2][3]);
      acc[3][0] = fma(z23.y, c01.x, acc[3][0]); acc[3][1] = fma(z23.y, c01.y, acc[3][1]);
      acc[3][2] = fma(z23.y, c23.x, acc[3][2]); acc[3][3] = fma(z23.y, c23.y, acc[3][3]);
    }
  }

  double inv[4];
#pragma unroll
  for (int j = 0; j < 4; ++j) inv[j] = invD[c0 + cgi * 4 + j];
#pragma unroll
  for (int i = 0; i < 4; ++i) {
    double b = acc[i][0] * inv[0]; int bi = c0 + cgi * 4;
#pragma unroll
    for (int j = 1; j < 4; ++j) {
      const double v = acc[i][j] * inv[j];
      if (v > b) { b = v; bi = c0 + cgi * 4 + j; }
    }
#pragma unroll
    for (int msk = 1; msk < 32; msk <<= 1) {
      const double ob = __shfl_xor(b, msk);
      const int    oi = __shfl_xor(bi, msk);
      if (ob > b || (ob == b && oi < bi)) { b = ob; bi = oi; }
    }
    const int prow = p0 + rg * 4 + i;
    if (cgi == 0 && prow < cnt) {
      ebest[(size_t)blockIdx.x * cap + prow] = b;
      eidx [(size_t)blockIdx.x * cap + prow] = bi;
    }
  }
}

__global__ __launch_bounds__(256)
void dist_exact_merge(const int* __restrict__ countp, int cap, const int* __restrict__ list,
                      const double* __restrict__ ebest, const int* __restrict__ eidx,
                      int* __restrict__ codes, int mod) {
  int cnt = *countp; cnt = cnt < cap ? cnt : cap;
  const int p = blockIdx.x * 256 + threadIdx.x;
  if (p >= cnt) return;
  double b = ebest[p]; int bi = eidx[p];
  for (int t = 1; t < 16; ++t) {
    const double v = ebest[(size_t)t * cap + p];
    if (v > b) { b = v; bi = eidx[(size_t)t * cap + p]; }
  }
  codes[(size_t)list[p] * 3 + mod] = bi;
}

__global__ __launch_bounds__(256)
void logits_exact(const int* __restrict__ candcountp, const int* __restrict__ cand,
                  const int* __restrict__ rowpos, const double* __restrict__ Hd,
                  const float* __restrict__ ksw,
                  double* __restrict__ cvalE, int* __restrict__ cidxE) {
  const int i = blockIdx.x * 4 + (threadIdx.x >> 6);
  const int lane = threadIdx.x & 63;
  int cc = *candcountp; cc = cc < CANDMAX ? cc : CANDMAX;
  if (i >= CANDMAX) return;
  if (i < cc) {
    const int r = cand[i];
    const double* h = Hd + (size_t)rowpos[r] * HID;
    double s = 0.0;
    for (int d = lane; d < HID; d += 64) s = fma(h[d], (double)ksw[d], s);
#pragma unroll
    for (int off = 32; off > 0; off >>= 1) s += __shfl_down(s, off, 64);
    if (lane == 0) { cvalE[i] = s; cidxE[i] = r; }
  } else if (lane == 0) {
    cvalE[i] = -1e300; cidxE[i] = 0x7FFFFFFF;
  }
}

__global__ void finalize2(const int* __restrict__ kidx, int* __restrict__ out) {
  const int t = threadIdx.x;
  const int k = kidx[t];
  out[NROWS * 3 + t] = k;
  int* sel = out + NROWS * 3 + TOPM;
  sel[t * 3 + 0] = out[(size_t)k * 3 + 0];
  sel[t * 3 + 1] = out[(size_t)k * 3 + 1];
  sel[t * 3 + 2] = out[(size_t)k * 3 + 2];
}

// =====================================================================
extern "C" void kernel_launch(void* const* d_in, const int* in_sizes, int n_in,
                              void* d_out, int out_size, void* d_ws, size_t ws_size,
                              hipStream_t stream) {
  const float* h0  = (const float*)d_in[0];
  const float* W1  = (const float*)d_in[1];
  const float* b1  = (const float*)d_in[2];
  const float* W2  = (const float*)d_in[3];
  const float* b2  = (const float*)d_in[4];
  const float* Wm  = (const float*)d_in[5];
  const float* bm  = (const float*)d_in[6];
  const float* Wt  = (const float*)d_in[7];
  const float* bt  = (const float*)d_in[8];
  const float* Wp  = (const float*)d_in[9];
  const float* bp  = (const float*)d_in[10];
  const float* Cm  = (const float*)d_in[11];
  const float* Ct  = (const float*)d_in[12];
  const float* Cp  = (const float*)d_in[13];
  const float* ksw = (const float*)d_in[14];
  int* out = (int*)d_out;

  size_t fixed = (size_t)NROWS * HID * 4 * 2
               + (size_t)3 * HID * DIN * 2
               + (size_t)4 * 3 * HID * HID * 2
               + (size_t)3 * 3 * CS * HID * 2
               + (size_t)16 * NROWS * 12
               + (size_t)NROWS * 24
               + (size_t)3 * CS * 12 + (8 << 20);
  long long rem = (long long)ws_size - (long long)fixed;
  int cap = (int)(rem / 17000);
  cap = cap < 1024 ? 1024 : (cap > 6144 ? 6144 : cap);
  cap &= ~63;

  char* ws = (char*)d_ws;
  size_t off = 0;
  auto alloc = [&](size_t bytes) { void* p = ws + off; off = (off + bytes + 255) & ~(size_t)255; return p; };
  double* Hd     = (double*)alloc((size_t)cap * HID * 8);
  double* H1d    = (double*)alloc((size_t)cap * HID * 8);   // reused as per-mod zd
  double* ebest  = (double*)alloc((size_t)16 * cap * 8);
  double* logits = (double*)alloc((size_t)NROWS * 8);
  double* cvalA  = (double*)alloc(8192 * 8);
  double* c2val  = (double*)alloc(2048 * 8);
  double* c3val  = (double*)alloc(256 * 8);
  double* cvalE  = (double*)alloc(CANDMAX * 8);
  double* kval   = (double*)alloc(256 * 8);
  double* invD   = (double*)alloc((size_t)3 * CS * 8);
  double* cut    = (double*)alloc(256);
  float* Hf      = (float*)alloc((size_t)NROWS * HID * 4);
  float* Zf      = (float*)alloc((size_t)NROWS * HID * 4);
  float* pb      = (float*)alloc((size_t)16 * NROWS * 4);
  float* ps      = (float*)alloc((size_t)16 * NROWS * 4);
  float* invF    = (float*)alloc((size_t)3 * CS * 4);
  float* zinv    = (float*)alloc((size_t)NROWS * 4);
  u16* w1t       = (u16*)alloc((size_t)3 * HID * DIN * 2);
  u16* w2t       = (u16*)alloc((size_t)3 * HID * HID * 2);
  u16* wmt       = (u16*)alloc((size_t)3 * HID * HID * 2);
  u16* wtt       = (u16*)alloc((size_t)3 * HID * HID * 2);
  u16* wpt       = (u16*)alloc((size_t)3 * HID * HID * 2);
  u16* cbp       = (u16*)alloc((size_t)3 * 3 * CS * HID * 2);
  int* pi        = (int*)alloc((size_t)16 * NROWS * 4);
  int* eidx      = (int*)alloc((size_t)16 * cap * 4);
  int* cidxA     = (int*)alloc(8192 * 4);
  int* c2idx     = (int*)alloc(2048 * 4);
  int* c3idx     = (int*)alloc(256 * 4);
  int* cidxE     = (int*)alloc(CANDMAX * 4);
  int* kidx      = (int*)alloc(256 * 4);
  int* flags     = (int*)alloc((size_t)NROWS * 4);
  int* rowpos    = (int*)alloc((size_t)NROWS * 4);
  int* ulist     = (int*)alloc((size_t)cap * 4);
  int* lm0       = (int*)alloc((size_t)cap * 4);
  int* lm1       = (int*)alloc((size_t)cap * 4);
  int* lm2       = (int*)alloc((size_t)cap * 4);
  int* cand      = (int*)alloc(CANDMAX * 4);
  int* counters  = (int*)alloc(64);

  const dim3 blk(256);
  const float* Wmods[3] = {Wm, Wt, Wp};
  const float* bmods[3] = {bm, bt, bp};
  const float* Cmods[3] = {Cm, Ct, Cp};
  u16* wmodt[3] = {wmt, wtt, wpt};
  int* listm[3] = {lm0, lm1, lm2};

  zero_init<<<dim3(NROWS / 256), blk, 0, stream>>>(flags, rowpos, counters);

  // ---- split weights (transposed) and codebooks ----
  const size_t p1 = (size_t)HID * DIN, pH = (size_t)HID * HID, pC = (size_t)CS * HID;
  split_t<<<dim3(HID / 32, DIN / 32), dim3(32, 8), 0, stream>>>(W1, w1t, w1t + p1, w1t + 2 * p1, DIN, HID);
  split_t<<<dim3(HID / 32, HID / 32), dim3(32, 8), 0, stream>>>(W2, w2t, w2t + pH, w2t + 2 * pH, HID, HID);
  for (int mod = 0; mod < 3; ++mod) {
    split_t<<<dim3(HID / 32, HID / 32), dim3(32, 8), 0, stream>>>(
        Wmods[mod], wmodt[mod], wmodt[mod] + pH, wmodt[mod] + 2 * pH, HID, HID);
    u16* cb = cbp + (size_t)mod * 3 * pC;
    split_nt<<<dim3((int)(pC / 4 / 256)), blk, 0, stream>>>(Cmods[mod], cb, cb + pC, cb + 2 * pC, (int)(pC / 4));
    codebook_invnorm<<<dim3(CS / 4), blk, 0, stream>>>(Cmods[mod], invD + mod * CS, invF + mod * CS, HID);
  }

  // ---- MFMA phase A ----
  gemm3<0, 3><<<dim3(HID / 128, NROWS / 128), blk, 0, stream>>>(
      h0, w1t, w1t + p1, w1t + 2 * p1, b1, Zf, nullptr, nullptr, nullptr, nullptr, HID, DIN);
  gemm3<0, 3><<<dim3(HID / 128, NROWS / 128), blk, 0, stream>>>(
      Zf, w2t, w2t + pH, w2t + 2 * pH, b2, Hf, nullptr, nullptr, nullptr, nullptr, HID, HID);
  row_logits<<<dim3(NROWS / 4), blk, 0, stream>>>(Hf, ksw, logits);

  for (int mod = 0; mod < 3; ++mod) {
    gemm3<1, 3><<<dim3(HID / 128, NROWS / 128), blk, 0, stream>>>(
        Hf, wmodt[mod], wmodt[mod] + pH, wmodt[mod] + 2 * pH, bmods[mod], Zf,
        nullptr, nullptr, nullptr, nullptr, HID, HID);
    zinv_rows<<<dim3(NROWS / 4), blk, 0, stream>>>(Zf, zinv);
    u16* cb = cbp + (size_t)mod * 3 * pC;
    gemm3<2, 2><<<dim3(CS / 128, NROWS / 128), blk, 0, stream>>>(
        Zf, cb, cb + pC, nullptr, nullptr, nullptr, invF + mod * CS, pb, ps, pi, CS, HID);
    merge_dist<<<dim3(NROWS / 256), blk, 0, stream>>>(pb, ps, pi, zinv, out, flags, mod);
  }

  // ---- approx top-k banding ----
  bitonic_topk<1024><<<dim3(32), blk, 0, stream>>>(logits, nullptr, cvalA, cidxA, 256);
  bitonic_topk<1024><<<dim3(8), blk, 0, stream>>>(cvalA, cidxA, c2val, c2idx, 256);
  bitonic_topk<2048><<<dim3(1), blk, 0, stream>>>(c2val, c2idx, c3val, c3idx, 256);
  cutoff_kernel<<<dim3(1), dim3(64), 0, stream>>>(c3val, cut);
  cand_flag<<<dim3(NROWS / 256), blk, 0, stream>>>(logits, cut, flags, cand, counters);
  build_lists<<<dim3(NROWS / 256), blk, 0, stream>>>(flags, ulist, rowpos, lm0, lm1, lm2, counters, cap);

  // ---- exact fp64 refine: encoder on union, proj+dist per modality ----
  gemm_rows_f64<true, 0><<<dim3(HID / 64, cap / 64), blk, 0, stream>>>(
      ulist, nullptr, counters, cap, h0, nullptr, W1, b1, H1d, DIN);
  gemm_rows_f64<true, 1><<<dim3(HID / 64, cap / 64), blk, 0, stream>>>(
      nullptr, nullptr, counters, cap, nullptr, H1d, W2, b2, Hd, HID);
  for (int mod = 0; mod < 3; ++mod) {
    gemm_rows_f64<false, 2><<<dim3(HID / 64, cap / 64), blk, 0, stream>>>(
        listm[mod], rowpos, counters + 2 + mod, cap, nullptr, Hd, Wmods[mod], bmods[mod], H1d, HID);
    dist_exact2<<<dim3(CS / 128, cap / 32), blk, 0, stream>>>(
        counters + 2 + mod, cap, H1d, Cmods[mod], invD + mod * CS, ebest, eidx);
    dist_exact_merge<<<dim3((cap + 255) / 256), blk, 0, stream>>>(
        counters + 2 + mod, cap, listm[mod], ebest, eidx, out, mod);
  }

  // ---- exact top-256 ----
  logits_exact<<<dim3(CANDMAX / 4), blk, 0, stream>>>(counters + 1, cand, rowpos, Hd, ksw, cvalE, cidxE);
  bitonic_topk<2048><<<dim3(1), blk, 0, stream>>>(cvalE, cidxE, kval, kidx, 256);
  finalize2<<<dim3(1), blk, 0, stream>>>(kidx, out);
}